// Round 21
// baseline (210.405 us; speedup 1.0000x reference)
//
#include <hip/hip_runtime.h>
#include <hip/hip_bf16.h>

// Problem dims (fixed)
#define B_ 2
#define L_ 2048
#define D_ 1024
#define E_ 2048
#define N_ 16
#define DR_ 64
#define DC_ 4
#define M_ (B_*L_)   // 4096 rows
#define SSEG 16      // scan segments
#define LSEG (L_/SSEG)  // 128
#define KS_ 8        // split-K factor for C96 GEMM
#define CH 32        // scan chunk (timesteps per barrier group)
#define LOG2E 1.4426950408889634f

typedef __attribute__((ext_vector_type(8))) short bf16x8;
typedef __attribute__((ext_vector_type(4))) float f32x4;

__device__ __forceinline__ ushort f2bf(float x){
    union { float f; unsigned u; } v; v.f = x;
    unsigned r = v.u + 0x7FFFu + ((v.u >> 16) & 1u);
    return (ushort)(r >> 16);
}
__device__ __forceinline__ float bf2f(ushort u){
    union { unsigned u; float f; } v; v.u = ((unsigned)u) << 16;
    return v.f;
}
// single v_exp_f32 (2^x)
__device__ __forceinline__ float fexp2(float x){
    float r;
    asm("v_exp_f32 %0, %1" : "=v"(r) : "v"(x));
    return r;
}
// fast silu via v_rcp_f32
__device__ __forceinline__ float fast_silu(float x){
    return x * __builtin_amdgcn_rcpf(1.f + __expf(-x));
}
// fast softplus
__device__ __forceinline__ float softplus_f(float z){
    return (z > 20.f) ? z : __logf(1.f + __expf(z));
}

// DPP cross-lane (VALU, zero DS traffic)
#define DPP_F(x, CTRL) __int_as_float(__builtin_amdgcn_update_dpp(0, __float_as_int(x), (CTRL), 0xf, 0xf, true))

// async global->LDS, 16B per lane
__device__ __forceinline__ void gld16(const void* g, void* l){
    __builtin_amdgcn_global_load_lds(
        (const __attribute__((address_space(1))) unsigned int*)g,
        (__attribute__((address_space(3))) unsigned int*)l,
        16, 0, 0);
}

// ---------------- fused weight prep (+ conv_w transpose) ----------------
#define PR0 (E_*D_/4)
#define PR1 (2*PR0)
#define PR2 (3*PR0)
#define PR3 (PR2 + E_*DR_/4)
#define PR4 (PR3 + DR_*E_/4)
#define PR5 (PR4 + N_*E_/4)
#define PR6 (PR5 + N_*E_/4)
#define PR7 (PR6 + 32*E_/4)
#define PR8 (PR7 + 4*E_/4)       // conv_w [E][4] -> cwT [4][E] f32
__global__ __launch_bounds__(256) void prep_k(const float* __restrict__ in_w,
                                              const float* __restrict__ skip_w,
                                              const float* __restrict__ out_w,
                                              const float* __restrict__ wd2,
                                              const float* __restrict__ wd1,
                                              const float* __restrict__ wB,
                                              const float* __restrict__ wC,
                                              const float* __restrict__ conv_w,
                                              ushort* __restrict__ wis,
                                              ushort* __restrict__ wo,
                                              ushort* __restrict__ wd2b,
                                              ushort* __restrict__ W96,
                                              float* __restrict__ cwT){
    int i = blockIdx.x * 256 + threadIdx.x;
    const float* src; ushort* dst; int off;
    if (i < PR0)      { src = in_w;   dst = wis;                       off = i; }
    else if (i < PR1) { src = skip_w; dst = wis + (size_t)E_*D_;       off = i - PR0; }
    else if (i < PR2) { src = out_w;  dst = wo;                        off = i - PR1; }
    else if (i < PR3) { src = wd2;    dst = wd2b;                      off = i - PR2; }
    else if (i < PR4) { src = wd1;    dst = W96;                       off = i - PR3; }
    else if (i < PR5) { src = wB;     dst = W96 + (size_t)64*E_;       off = i - PR4; }
    else if (i < PR6) { src = wC;     dst = W96 + (size_t)80*E_;       off = i - PR5; }
    else if (i < PR7) {
        ushort4 z = {0,0,0,0};
        ((ushort4*)(W96 + (size_t)96*E_))[i - PR6] = z;
        return;
    } else if (i < PR8) {
        int u = i - PR7;
        int k = u >> 9;            // tap
        int g = u & 511;           // e-quad
        float4 o;
        o.x = conv_w[(g*4 + 0)*4 + k];
        o.y = conv_w[(g*4 + 1)*4 + k];
        o.z = conv_w[(g*4 + 2)*4 + k];
        o.w = conv_w[(g*4 + 3)*4 + k];
        ((float4*)(cwT + (size_t)k * E_))[g] = o;
        return;
    } else return;
    float4 v = ((const float4*)src)[off];
    ushort4 o;
    o.x = f2bf(v.x); o.y = f2bf(v.y); o.z = f2bf(v.z); o.w = f2bf(v.w);
    ((ushort4*)dst)[off] = o;
}

// ---------------- RMSNorm -> bf16 ----------------
__global__ __launch_bounds__(256) void rmsnorm_k(const float* __restrict__ resid,
                                                 const float* __restrict__ norm_w,
                                                 ushort* __restrict__ xn){
    int row = blockIdx.x;
    const float4* r = (const float4*)(resid + (size_t)row * D_);
    float4 v = r[threadIdx.x];
    float ss = v.x*v.x + v.y*v.y + v.z*v.z + v.w*v.w;
    for (int m = 32; m; m >>= 1) ss += __shfl_xor(ss, m);
    __shared__ float sred[4];
    if ((threadIdx.x & 63) == 0) sred[threadIdx.x >> 6] = ss;
    __syncthreads();
    float tot = sred[0] + sred[1] + sred[2] + sred[3];
    float scale = rsqrtf(tot / (float)D_ + 1e-5f);
    const float4* wv = (const float4*)norm_w;
    float4 w = wv[threadIdx.x];
    ushort4 o;
    o.x = f2bf(v.x * scale * w.x);
    o.y = f2bf(v.y * scale * w.y);
    o.z = f2bf(v.z * scale * w.z);
    o.w = f2bf(v.w * scale * w.w);
    ((ushort4*)(xn + (size_t)row * D_))[threadIdx.x] = o;
}

// ---------------- GEMM machinery ----------------
#define BM 128
#define BN 128
#define BK 64
#define DBK 32   // dual-GEMM K-step (r21: halved so dbuf LDS = 32KB -> 5 blocks/CU;
                 // r20 was 64KB -> 2 blocks/CU = latency-bound at 20% occupancy)

// fused in-proj + skip-proj; 2D XCD chunk; BK=32 double-buffered.
// Row chunks: 4 x 16B per 32-col row; stage swizzle c_global=(c ^ (row&3)),
// read chunk = (lane>>4) ^ (krow&3) -- bijective per row, banks 4-way spread.
__global__ __launch_bounds__(256)
void gemm_dual_k(const ushort* __restrict__ A, const ushort* __restrict__ Bm,
                 ushort* __restrict__ P1, ushort* __restrict__ P2){
    __shared__ __align__(16) ushort As[2][BM * DBK];
    __shared__ __align__(16) ushort Bs[2][BN * DBK];
    const int xcd = blockIdx.x & 7;
    const int idx = blockIdx.x >> 3;                      // 0..127
    const int row0 = (((xcd >> 2) << 4) + (idx >> 3)) * BM;   // rows 0..31
    const int col0 = (((xcd & 3) << 3) + (idx & 7)) * BN;     // cols 0..31
    const int tid = threadIdx.x;
    const int lane = tid & 63;
    const int wid = tid >> 6;
    const int wm = wid >> 1, wn = wid & 1;
    f32x4 acc[4][4] = {};
    const int lr = lane >> 2;                       // row within 16-row group
    const int cs = ((lane & 3) ^ (lr & 3)) * 8;     // XOR-swizzled source chunk

    const int NK = D_ / DBK;   // 32
    #pragma unroll
    for (int i = 0; i < 2; ++i){
        const int R0 = wid * 32 + i * 16;
        gld16(A + (size_t)(row0 + R0 + lr) * D_ + cs, &As[0][R0 * DBK]);
        gld16(Bm + (size_t)(col0 + R0 + lr) * D_ + cs, &Bs[0][R0 * DBK]);
    }
    __syncthreads();
    int cur = 0;
    for (int ki = 0; ki < NK; ++ki){
        if (ki + 1 < NK){
            const int k0 = (ki + 1) * DBK;
            #pragma unroll
            for (int i = 0; i < 2; ++i){
                const int R0 = wid * 32 + i * 16;
                gld16(A + (size_t)(row0 + R0 + lr) * D_ + k0 + cs, &As[cur^1][R0 * DBK]);
                gld16(Bm + (size_t)(col0 + R0 + lr) * D_ + k0 + cs, &Bs[cur^1][R0 * DBK]);
            }
        }
        {
            bf16x8 af[4], bfr[4];
            const int krow = lane & 15;
            const int kcol = (((lane >> 4)) ^ (krow & 3)) * 8;
            #pragma unroll
            for (int mi = 0; mi < 4; ++mi)
                af[mi] = *(const bf16x8*)(&As[cur][(wm*64 + mi*16 + krow) * DBK + kcol]);
            #pragma unroll
            for (int ni = 0; ni < 4; ++ni)
                bfr[ni] = *(const bf16x8*)(&Bs[cur][(wn*64 + ni*16 + krow) * DBK + kcol]);
            #pragma unroll
            for (int mi = 0; mi < 4; ++mi)
                #pragma unroll
                for (int ni = 0; ni < 4; ++ni)
                    acc[mi][ni] = __builtin_amdgcn_mfma_f32_16x16x32_bf16(af[mi], bfr[ni], acc[mi][ni], 0, 0, 0);
        }
        __syncthreads();
        cur ^= 1;
    }
    ushort* base = (col0 < E_) ? P1 : P2;
    const int cb = (col0 < E_) ? col0 : col0 - E_;
    #pragma unroll
    for (int mi = 0; mi < 4; ++mi)
        #pragma unroll
        for (int ni = 0; ni < 4; ++ni)
            #pragma unroll
            for (int j = 0; j < 4; ++j){
                int r = row0 + wm*64 + mi*16 + (lane >> 4) * 4 + j;
                int c = cb + wn*64 + ni*16 + (lane & 15);
                base[(size_t)r * E_ + c] = f2bf(acc[mi][ni][j]);
            }
}

// out-proj: BM=64 -> 512 blocks, XCD swizzle, BK=64 dbuf (r20 form)
#define OBM 64
__global__ __launch_bounds__(256)
void gemm_out_k(const ushort* __restrict__ A, const ushort* __restrict__ Bm,
                float* __restrict__ Cp, const float* __restrict__ aux){
    __shared__ __align__(16) ushort As[2][OBM * BK];
    __shared__ __align__(16) ushort Bs[2][BN * BK];
    const int wid9 = (blockIdx.x & 7) * 64 + (blockIdx.x >> 3);  // nwg=512, bijective
    const int col0 = (wid9 & 7) * BN;
    const int row0 = (wid9 >> 3) * OBM;
    const int tid = threadIdx.x;
    const int lane = tid & 63;
    const int wid = tid >> 6;
    const int wm = wid >> 1, wn = wid & 1;   // wave tile 32x64
    f32x4 acc[2][4] = {};
    const int l8 = lane >> 3;
    const int cs = ((lane & 7) ^ (l8 & 7)) * 8;

    const int NK = E_ / BK;   // 32
    #pragma unroll
    for (int i = 0; i < 2; ++i){
        const int R0 = wid * 16 + i * 8;
        gld16(A + (size_t)(row0 + R0 + l8) * E_ + cs, &As[0][R0 * BK]);
    }
    #pragma unroll
    for (int i = 0; i < 4; ++i){
        const int R0 = wid * 32 + i * 8;
        gld16(Bm + (size_t)(col0 + R0 + l8) * E_ + cs, &Bs[0][R0 * BK]);
    }
    __syncthreads();
    int cur = 0;
    for (int ki = 0; ki < NK; ++ki){
        if (ki + 1 < NK){
            const int k0 = (ki + 1) * BK;
            #pragma unroll
            for (int i = 0; i < 2; ++i){
                const int R0 = wid * 16 + i * 8;
                gld16(A + (size_t)(row0 + R0 + l8) * E_ + k0 + cs, &As[cur^1][R0 * BK]);
            }
            #pragma unroll
            for (int i = 0; i < 4; ++i){
                const int R0 = wid * 32 + i * 8;
                gld16(Bm + (size_t)(col0 + R0 + l8) * E_ + k0 + cs, &Bs[cur^1][R0 * BK]);
            }
        }
        #pragma unroll
        for (int kk = 0; kk < 2; ++kk){
            bf16x8 af[2], bfr[4];
            const int krow = lane & 15;
            const int kcol = ((kk * 4 + (lane >> 4)) ^ (krow & 7)) * 8;
            #pragma unroll
            for (int mi = 0; mi < 2; ++mi)
                af[mi] = *(const bf16x8*)(&As[cur][(wm*32 + mi*16 + krow) * BK + kcol]);
            #pragma unroll
            for (int ni = 0; ni < 4; ++ni)
                bfr[ni] = *(const bf16x8*)(&Bs[cur][(wn*64 + ni*16 + krow) * BK + kcol]);
            #pragma unroll
            for (int mi = 0; mi < 2; ++mi)
                #pragma unroll
                for (int ni = 0; ni < 4; ++ni)
                    acc[mi][ni] = __builtin_amdgcn_mfma_f32_16x16x32_bf16(af[mi], bfr[ni], acc[mi][ni], 0, 0, 0);
        }
        __syncthreads();
        cur ^= 1;
    }
    #pragma unroll
    for (int mi = 0; mi < 2; ++mi)
        #pragma unroll
        for (int ni = 0; ni < 4; ++ni)
            #pragma unroll
            for (int j = 0; j < 4; ++j){
                int r = row0 + wm*32 + mi*16 + (lane >> 4) * 4 + j;
                int c = col0 + wn*64 + ni*16 + (lane & 15);
                size_t idx = (size_t)r * D_ + c;
                Cp[idx] = acc[mi][ni][j] + aux[idx];
            }
}

// ---------------- C96 GEMM, split-K, CBM=64 ----------------
#define CBM 64
__global__ __launch_bounds__(256)
void gemm_c96_sk(const ushort* __restrict__ A, const ushort* __restrict__ Bm,
                 float* __restrict__ part){
    __shared__ __align__(16) ushort As[CBM * BK];
    __shared__ __align__(16) ushort Bs[128 * BK];
    const int ks = blockIdx.x;
    const int row0 = blockIdx.y * CBM;
    const int tid = threadIdx.x;
    const int lane = tid & 63;
    const int wid = tid >> 6;
    const int wm = wid >> 1, wn = wid & 1;   // wave tile 32x64
    f32x4 acc[2][4] = {};
    const int l8 = lane >> 3;
    const int cs = ((lane & 7) ^ (l8 & 7)) * 8;

    for (int k0 = ks * (E_ / KS_); k0 < (ks + 1) * (E_ / KS_); k0 += BK){
        #pragma unroll
        for (int i = 0; i < 2; ++i){
            const int R0 = wid * 16 + i * 8;
            gld16(A + (size_t)(row0 + R0 + l8) * E_ + k0 + cs, As + R0 * BK);
        }
        #pragma unroll
        for (int i = 0; i < 4; ++i){
            const int R0 = wid * 32 + i * 8;
            gld16(Bm + (size_t)(R0 + l8) * E_ + k0 + cs, Bs + R0 * BK);
        }
        __syncthreads();
        #pragma unroll
        for (int kk = 0; kk < 2; ++kk){
            bf16x8 af[2], bfr[4];
            const int krow = lane & 15;
            const int kcol = ((kk * 4 + (lane >> 4)) ^ (krow & 7)) * 8;
            #pragma unroll
            for (int mi = 0; mi < 2; ++mi)
                af[mi] = *(const bf16x8*)(As + (wm*32 + mi*16 + krow) * BK + kcol);
            #pragma unroll
            for (int ni = 0; ni < 4; ++ni)
                bfr[ni] = *(const bf16x8*)(Bs + (wn*64 + ni*16 + krow) * BK + kcol);
            #pragma unroll
            for (int mi = 0; mi < 2; ++mi)
                #pragma unroll
                for (int ni = 0; ni < 4; ++ni)
                    acc[mi][ni] = __builtin_amdgcn_mfma_f32_16x16x32_bf16(af[mi], bfr[ni], acc[mi][ni], 0, 0, 0);
        }
        __syncthreads();
    }
    float* dst = part + (size_t)ks * M_ * 128;
    #pragma unroll
    for (int mi = 0; mi < 2; ++mi)
        #pragma unroll
        for (int ni = 0; ni < 4; ++ni)
            #pragma unroll
            for (int j = 0; j < 4; ++j){
                int r = row0 + wm*32 + mi*16 + (lane >> 4) * 4 + j;
                int c = wn*64 + ni*16 + (lane & 15);
                dst[(size_t)r * 128 + c] = acc[mi][ni][j];
            }
}

__global__ __launch_bounds__(256) void c96_reduce_k(const float* __restrict__ part,
                                                    ushort* __restrict__ C96){
    int i4 = blockIdx.x * 256 + threadIdx.x;     // over M_*128/4
    float4 a = *(const float4*)(part + (size_t)i4 * 4);
    #pragma unroll
    for (int k = 1; k < KS_; ++k){
        float4 b = *(const float4*)(part + (size_t)k * M_ * 128 + (size_t)i4 * 4);
        a.x += b.x; a.y += b.y; a.z += b.z; a.w += b.w;
    }
    ushort4 o;
    o.x = f2bf(a.x); o.y = f2bf(a.y); o.z = f2bf(a.z); o.w = f2bf(a.w);
    *(ushort4*)(C96 + (size_t)i4 * 4) = o;
}

// ---------------- causal depthwise conv1d + silu -> bf16 (coalesced taps) ----------------
__global__ __launch_bounds__(256) void conv_silu_k(const ushort* __restrict__ xpre,
                                                   const float* __restrict__ cwT,
                                                   const float* __restrict__ conv_b,
                                                   ushort* __restrict__ xb){
    int i4 = blockIdx.x * 256 + threadIdx.x;
    if (i4 >= M_ * E_ / 4) return;
    int idx = i4 * 4;
    int e = idx & (E_ - 1);
    int bl = idx >> 11;
    int t = bl & (L_ - 1);
    float4 b4 = *(const float4*)(conv_b + e);
    float a0 = b4.x, a1 = b4.y, a2 = b4.z, a3 = b4.w;
    #pragma unroll
    for (int k = 0; k < 4; ++k){
        int dt = 3 - k;
        if (t >= dt){
            ushort4 xv = *(const ushort4*)(xpre + idx - dt * E_);
            float4 wv = *(const float4*)(cwT + (size_t)k * E_ + e);
            a0 += bf2f(xv.x) * wv.x;
            a1 += bf2f(xv.y) * wv.y;
            a2 += bf2f(xv.z) * wv.z;
            a3 += bf2f(xv.w) * wv.w;
        }
    }
    ushort4 sb;
    sb.x = f2bf(fast_silu(a0));
    sb.y = f2bf(fast_silu(a1));
    sb.z = f2bf(fast_silu(a2));
    sb.w = f2bf(fast_silu(a3));
    *(ushort4*)(xb + idx) = sb;
}

// ---------------- chunk-parallel selective scan, delta fused via MFMA ----------------
#define SF2 36   // f32 tile stride (144B, 16B-aligned)
#define SYD 20   // sy stride

__device__ __forceinline__ void seg_swz(int& b, int& s, int& e0){
    int lin = blockIdx.x + 128 * (blockIdx.y + 16 * blockIdx.z);   // nwg = 4096
    int swz = (lin & 7) * 512 + (lin >> 3);                        // bijective
    e0 = (swz & 127) * 16;
    s  = (swz >> 7) & 15;
    b  = swz >> 11;
}

// grid (E_/16, SSEG, B_), block 256 = 16 e x 16 n
__global__ __launch_bounds__(256, 8) void seg1_k(const ushort* __restrict__ xb,
                                              const ushort* __restrict__ C96,
                                              const ushort* __restrict__ wd2b,
                                              const float* __restrict__ wd2_bias,
                                              const float* __restrict__ A_log,
                                              float* __restrict__ F,
                                              float* __restrict__ segdt){
    int b, s, e0; seg_swz(b, s, e0);
    const int tid = threadIdx.x;
    const int lane = tid & 63, wid = tid >> 6;
    const int n = tid & 15, ei = tid >> 4;
    const int e = e0 + ei;
    const float Aen2 = -__expf(A_log[e * N_ + n]) * LOG2E;
    float h = 0.f;
    __shared__ __align__(16) ushort sxr[CH][72];
    __shared__ __align__(16) ushort swd2[16][72];
    __shared__ __align__(16) ushort sxu[16][40];
    __shared__ float sd[16][SF2], sdx[16][SF2], sB[16][SF2];
    __shared__ float ssdt[2][16];
    const int tq = tid >> 3, qc = tid & 7;   // row 0..31, col-group 0..7

    if (tid < 128){
        int r = tid >> 3, cc = (tid & 7) * 8;
        *(uint4*)&swd2[r][cc] = *(const uint4*)(wd2b + (size_t)(e0 + r) * DR_ + cc);
    }
    const float bias = wd2_bias[e0 + (lane & 15)];
    float psdt = 0.f;   // producer-lane partial sum of delta over its t-slice

    for (int c = 0; c < LSEG / CH; ++c){
        int t0 = s * LSEG + c * CH;
        size_t row = (size_t)(b * L_ + t0 + tq);
        *(uint4*)&sxr[tq][qc * 8] = *(const uint4*)(C96 + row * 128 + qc * 8);
        ushort2 rB = *(const ushort2*)(C96 + row * 128 + 64 + qc * 2);
        ushort2 xu = *(const ushort2*)(xb + row * E_ + e0 + qc * 2);
        sB[qc*2+0][tq] = bf2f(rB.x); sB[qc*2+1][tq] = bf2f(rB.y);
        sxu[qc*2+0][tq] = xu.x; sxu[qc*2+1][tq] = xu.y;
        __syncthreads();
        // fused delta: waves 0,1 each compute one 16-t x 16-e tile
        if (wid < 2){
            f32x4 dacc = {};
            #pragma unroll
            for (int kk = 0; kk < 2; ++kk){
                bf16x8 af = *(const bf16x8*)&sxr[wid*16 + (lane & 15)][kk*32 + (lane >> 4)*8];
                bf16x8 bf = *(const bf16x8*)&swd2[lane & 15][kk*32 + (lane >> 4)*8];
                dacc = __builtin_amdgcn_mfma_f32_16x16x32_bf16(af, bf, dacc, 0, 0, 0);
            }
            const int crow = lane & 15;
            const int ttc = wid*16 + (lane >> 4)*4;
            float4 dv;
            dv.x = softplus_f(dacc[0] + bias);
            dv.y = softplus_f(dacc[1] + bias);
            dv.z = softplus_f(dacc[2] + bias);
            dv.w = softplus_f(dacc[3] + bias);
            *(float4*)&sd[crow][ttc] = dv;
            psdt += dv.x + dv.y + dv.z + dv.w;
            ushort4 xu4 = *(const ushort4*)&sxu[crow][ttc];
            float4 dxv;
            dxv.x = dv.x * bf2f(xu4.x); dxv.y = dv.y * bf2f(xu4.y);
            dxv.z = dv.z * bf2f(xu4.z); dxv.w = dv.w * bf2f(xu4.w);
            *(float4*)&sdx[crow][ttc] = dxv;
        }
        __syncthreads();
        #pragma unroll
        for (int t = 0; t < CH; t += 4){
            float4 d4  = *(const float4*)&sd[ei][t];
            float4 dx4 = *(const float4*)&sdx[ei][t];
            float4 b4  = *(const float4*)&sB[n][t];
            h = fexp2(d4.x*Aen2)*h + dx4.x*b4.x;
            h = fexp2(d4.y*Aen2)*h + dx4.y*b4.y;
            h = fexp2(d4.z*Aen2)*h + dx4.z*b4.z;
            h = fexp2(d4.w*Aen2)*h + dx4.w*b4.w;
        }
        __syncthreads();
    }
    // producer-lane sdt reduce
    if (wid < 2){
        psdt += __shfl_xor(psdt, 16);
        psdt += __shfl_xor(psdt, 32);
        if (lane < 16) ssdt[wid][lane] = psdt;
    }
    size_t base = ((size_t)(b * SSEG + s) * E_ + e) * N_ + n;
    F[base] = h;
    __syncthreads();
    if (tid < 16)
        segdt[(size_t)(b * SSEG + s) * E_ + e0 + tid] = ssdt[0][tid] + ssdt[1][tid];
}

// sequential carry over SSEG segments per (b,e,n)
__global__ __launch_bounds__(256) void carry_k(const float* __restrict__ F,
                                               const float* __restrict__ segdt,
                                               const float* __restrict__ A_log,
                                               float* __restrict__ carr){
    int idx = blockIdx.x * 256 + threadIdx.x;
    int n = idx & 15;
    int e = (idx >> 4) & (E_ - 1);
    int b = idx >> 15;
    const float Aen2 = -__expf(A_log[e * N_ + n]) * LOG2E;
    float c = 0.f;
    #pragma unroll
    for (int s = 0; s < SSEG; ++s){
        size_t base = ((size_t)(b * SSEG + s) * E_ + e) * N_ + n;
        carr[base] = c;
        float P = fexp2(Aen2 * segdt[(size_t)(b * SSEG + s) * E_ + e]);
        c = P * c + F[base];
    }
}

// grid (E_/16, SSEG, B_), block 256; gate fused into store
__global__ __launch_bounds__(256, 8) void seg2_k(const ushort* __restrict__ xb,
                                              const ushort* __restrict__ C96,
                                              const ushort* __restrict__ wd2b,
                                              const float* __restrict__ wd2_bias,
                                              const float* __restrict__ A_log,
                                              const float* __restrict__ carr,
                                              const ushort* __restrict__ skipb,
                                              const float* __restrict__ W_D,
                                              ushort* __restrict__ y2){
    int b, s, e0; seg_swz(b, s, e0);
    const int tid = threadIdx.x;
    const int lane = tid & 63, wid = tid >> 6;
    const int n = tid & 15, ei = tid >> 4;
    const int e = e0 + ei;
    const float Aen2 = -__expf(A_log[e * N_ + n]) * LOG2E;
    float h = carr[((size_t)(b * SSEG + s) * E_ + e) * N_ + n];
    __shared__ __align__(16) ushort sxr[CH][72];
    __shared__ __align__(16) ushort swd2[16][72];
    __shared__ __align__(16) ushort sxu[16][40];
    __shared__ float sd[16][SF2], sdx[16][SF2], sB[16][SF2], sC[16][SF2];
    __shared__ float sy[CH][SYD];
    const int tq = tid >> 3, qc = tid & 7;

    if (tid < 128){
        int r = tid >> 3, cc = (tid & 7) * 8;
        *(uint4*)&swd2[r][cc] = *(const uint4*)(wd2b + (size_t)(e0 + r) * DR_ + cc);
    }
    const float bias = wd2_bias[e0 + (lane & 15)];
    const float wv0 = W_D[e0 + qc * 2], wv1 = W_D[e0 + qc * 2 + 1];

    for (int c = 0; c < LSEG / CH; ++c){
        int t0 = s * LSEG + c * CH;
        size_t row = (size_t)(b * L_ + t0 + tq);
        *(uint4*)&sxr[tq][qc * 8] = *(const uint4*)(C96 + row * 128 + qc * 8);
        ushort2 rB = *(const ushort2*)(C96 + row * 128 + 64 + qc * 2);
        ushort2 rC = *(const ushort2*)(C96 + row * 128 + 80 + qc * 2);
        ushort2 xu = *(const ushort2*)(xb + row * E_ + e0 + qc * 2);
        ushort2 sv_pre = *(const ushort2*)(skipb + row * E_ + e0 + qc * 2);  // gate prefetch
        sB[qc*2+0][tq] = bf2f(rB.x); sB[qc*2+1][tq] = bf2f(rB.y);
        sC[qc*2+0][tq] = bf2f(rC.x); sC[qc*2+1][tq] = bf2f(rC.y);
        sxu[qc*2+0][tq] = xu.x; sxu[qc*2+1][tq] = xu.y;
        __syncthreads();
        if (wid < 2){
            f32x4 dacc = {};
            #pragma unroll
            for (int kk = 0; kk < 2; ++kk){
                bf16x8 af = *(const bf16x8*)&sxr[wid*16 + (lane & 15)][kk*32 + (lane >> 4)*8];
                bf16x8 bf = *(const bf16x8*)&swd2[lane & 15][kk*32 + (lane >> 4)*8];
                dacc = __builtin_amdgcn_mfma_f32_16x16x32_bf16(af, bf, dacc, 0, 0, 0);
            }
            const int crow = lane & 15;
            const int ttc = wid*16 + (lane >> 4)*4;
            float4 dv;
            dv.x = softplus_f(dacc[0] + bias);
            dv.y = softplus_f(dacc[1] + bias);
            dv.z = softplus_f(dacc[2] + bias);
            dv.w = softplus_f(dacc[3] + bias);
            *(float4*)&sd[crow][ttc] = dv;
            ushort4 xu4 = *(const ushort4*)&sxu[crow][ttc];
            float4 dxv;
            dxv.x = dv.x * bf2f(xu4.x); dxv.y = dv.y * bf2f(xu4.y);
            dxv.z = dv.z * bf2f(xu4.z); dxv.w = dv.w * bf2f(xu4.w);
            *(float4*)&sdx[crow][ttc] = dxv;
        }
        __syncthreads();
        #pragma unroll
        for (int t = 0; t < CH; t += 4){
            float4 d4  = *(const float4*)&sd[ei][t];
            float4 dx4 = *(const float4*)&sdx[ei][t];
            float4 b4  = *(const float4*)&sB[n][t];
            float4 c4  = *(const float4*)&sC[n][t];
            float y0, y1, y2v, y3;
            h = fexp2(d4.x*Aen2)*h + dx4.x*b4.x;  y0 = h * c4.x;
            h = fexp2(d4.y*Aen2)*h + dx4.y*b4.y;  y1 = h * c4.y;
            h = fexp2(d4.z*Aen2)*h + dx4.z*b4.z;  y2v = h * c4.z;
            h = fexp2(d4.w*Aen2)*h + dx4.w*b4.w;  y3 = h * c4.w;
            // 4-value 16-lane reduce via DPP (zero DS), bit-identical to xor butterfly
            float s01 = (n & 1) ? y0 : y1;
            float r01 = DPP_F(s01, 0xB1);        // quad_perm [1,0,3,2] == xor1
            float s23 = (n & 1) ? y2v : y3;
            float r23 = DPP_F(s23, 0xB1);
            float va, vb;
            if (n & 1){ va = y1 + r01; vb = y3 + r23; }
            else      { va = y0 + r01; vb = y2v + r23; }
            float s2 = (n & 2) ? va : vb;
            float r2 = DPP_F(s2, 0x4E);          // quad_perm [2,3,0,1] == xor2
            float v = ((n & 2) ? vb : va) + r2;
            v += DPP_F(v, 0x124);                // row_ror:4  (xor4-equivalent sum)
            v += DPP_F(v, 0x128);                // row_ror:8  (xor8-equivalent sum)
            if (n < 4) sy[t + n][ei] = v;
        }
        __syncthreads();
        {
            // fused gate: y2 = (y + W_D*x) * silu(skip) -> bf16 (skip prefetched)
            size_t orow = (size_t)(b * L_ + t0 + tq);
            float yv0 = sy[tq][qc*2], yv1 = sy[tq][qc*2+1];
            float xs0 = bf2f(sxu[qc*2+0][tq]), xs1 = bf2f(sxu[qc*2+1][tq]);
            float sk0 = bf2f(sv_pre.x), sk1 = bf2f(sv_pre.y);
            ushort2 o;
            o.x = f2bf((yv0 + wv0 * xs0) * fast_silu(sk0));
            o.y = f2bf((yv1 + wv1 * xs1) * fast_silu(sk1));
            *(ushort2*)(y2 + orow * E_ + e0 + qc * 2) = o;
        }
        __syncthreads();
    }
}

// ---------------- launch ----------------
extern "C" void kernel_launch(void* const* d_in, const int* in_sizes, int n_in,
                              void* d_out, int out_size, void* d_ws, size_t ws_size,
                              hipStream_t stream){
    const float* resid  = (const float*)d_in[0];
    const float* norm_w = (const float*)d_in[1];
    const float* skip_w = (const float*)d_in[2];
    const float* in_w   = (const float*)d_in[3];
    const float* conv_w = (const float*)d_in[4];
    const float* conv_b = (const float*)d_in[5];
    const float* wd1    = (const float*)d_in[6];
    const float* wd2    = (const float*)d_in[7];
    const float* wd2_b  = (const float*)d_in[8];
    const float* wB     = (const float*)d_in[9];
    const float* wC     = (const float*)d_in[10];
    const float* A_log  = (const float*)d_in[11];
    const float* W_D    = (const float*)d_in[12];
    const float* out_w  = (const float*)d_in[13];
    float* out = (float*)d_out;

    char* ws = (char*)d_ws;
    size_t off = 0;
    auto alloc = [&](size_t bytes) -> char* {
        char* p = ws + off;
        off += (bytes + 255) & ~(size_t)255;
        return p;
    };
    char* alias_base = ws;
    ushort* wis_b   = (ushort*)alloc((size_t)2 * E_ * D_ * 2);  // 8MB stacked [in_w; skip_w]
    ushort* xn_b    = (ushort*)alloc((size_t)M_ * D_ * 2);      // 8MB
    ushort* xpre_b  = (ushort*)alloc((size_t)M_ * E_ * 2);      // 16MB
    float*  part_buf= (float*)alias_base;                       // 16MB alias (KS_*M_*128*4)
    ushort* wo_b    = (ushort*)alloc((size_t)D_ * E_ * 2);       // 4MB
    ushort* wd2_bf  = (ushort*)alloc((size_t)E_ * DR_ * 2);      // 256KB
    ushort* W96_b   = (ushort*)alloc((size_t)128 * E_ * 2);      // 512KB
    float*  cwT_b   = (float*)alloc((size_t)4 * E_ * 4);         // 32KB transposed taps
    ushort* skip_b  = (ushort*)alloc((size_t)M_ * E_ * 2);       // 16MB
    ushort* xb_b    = (ushort*)alloc((size_t)M_ * E_ * 2);       // 16MB
    ushort* C96_b   = (ushort*)alloc((size_t)M_ * 128 * 2);      // 1MB
    float*  scr     = (float*)alloc((size_t)9 * 1024 * 1024);    // 9MB scratch
    ushort* y2_b    = (ushort*)alloc((size_t)M_ * E_ * 2);       // 16MB
    float* F_buf    = scr;
    float* carr_buf = scr + (size_t)B_ * SSEG * E_ * N_;
    float* segdt_buf= scr + (size_t)2 * B_ * SSEG * E_ * N_;
    (void)ws_size; (void)in_sizes; (void)n_in; (void)out_size;

    const int thr = 256;

    prep_k<<<(PR8 + 255)/256, thr, 0, stream>>>(in_w, skip_w, out_w, wd2, wd1, wB, wC, conv_w,
                                                wis_b, wo_b, wd2_bf, W96_b, cwT_b);

    rmsnorm_k<<<M_, thr, 0, stream>>>(resid, norm_w, xn_b);

    gemm_dual_k<<<1024, thr, 0, stream>>>(xn_b, wis_b, xpre_b, skip_b);

    conv_silu_k<<<(M_*E_/4 + 255)/256, thr, 0, stream>>>(xpre_b, cwT_b, conv_b, xb_b);

    gemm_c96_sk<<<dim3(KS_, M_/CBM), thr, 0, stream>>>(xb_b, W96_b, part_buf);
    c96_reduce_k<<<(M_*128/4)/256, thr, 0, stream>>>(part_buf, C96_b);

    seg1_k<<<dim3(E_/16, SSEG, B_), thr, 0, stream>>>(xb_b, C96_b, wd2_bf, wd2_b, A_log, F_buf, segdt_buf);
    carry_k<<<(B_*E_*N_)/256, thr, 0, stream>>>(F_buf, segdt_buf, A_log, carr_buf);
    seg2_k<<<dim3(E_/16, SSEG, B_), thr, 0, stream>>>(xb_b, C96_b, wd2_bf, wd2_b, A_log, carr_buf,
                                                      skip_b, W_D, y2_b);

    gemm_out_k<<<512, thr, 0, stream>>>(y2_b, wo_b, out, resid);
}

// Round 22
// 194.710 us; speedup vs baseline: 1.0806x; 1.0806x over previous
//
#include <hip/hip_runtime.h>
#include <hip/hip_bf16.h>

// Problem dims (fixed)
#define B_ 2
#define L_ 2048
#define D_ 1024
#define E_ 2048
#define N_ 16
#define DR_ 64
#define DC_ 4
#define M_ (B_*L_)   // 4096 rows
#define SSEG 16      // scan segments
#define LSEG (L_/SSEG)  // 128
#define KS_ 8        // split-K factor for C96 GEMM
#define CH 32        // scan chunk (timesteps per barrier group)
#define LOG2E 1.4426950408889634f

typedef __attribute__((ext_vector_type(8))) short bf16x8;
typedef __attribute__((ext_vector_type(4))) float f32x4;

__device__ __forceinline__ ushort f2bf(float x){
    union { float f; unsigned u; } v; v.f = x;
    unsigned r = v.u + 0x7FFFu + ((v.u >> 16) & 1u);
    return (ushort)(r >> 16);
}
__device__ __forceinline__ float bf2f(ushort u){
    union { unsigned u; float f; } v; v.u = ((unsigned)u) << 16;
    return v.f;
}
// single v_exp_f32 (2^x)
__device__ __forceinline__ float fexp2(float x){
    float r;
    asm("v_exp_f32 %0, %1" : "=v"(r) : "v"(x));
    return r;
}
// fast silu via v_rcp_f32
__device__ __forceinline__ float fast_silu(float x){
    return x * __builtin_amdgcn_rcpf(1.f + __expf(-x));
}
// fast softplus
__device__ __forceinline__ float softplus_f(float z){
    return (z > 20.f) ? z : __logf(1.f + __expf(z));
}

// DPP cross-lane (VALU, zero DS traffic)
#define DPP_F(x, CTRL) __int_as_float(__builtin_amdgcn_update_dpp(0, __float_as_int(x), (CTRL), 0xf, 0xf, true))

// async global->LDS, 16B per lane
__device__ __forceinline__ void gld16(const void* g, void* l){
    __builtin_amdgcn_global_load_lds(
        (const __attribute__((address_space(1))) unsigned int*)g,
        (__attribute__((address_space(3))) unsigned int*)l,
        16, 0, 0);
}

// ---------------- fused weight prep (+ conv_w transpose) ----------------
#define PR0 (E_*D_/4)
#define PR1 (2*PR0)
#define PR2 (3*PR0)
#define PR3 (PR2 + E_*DR_/4)
#define PR4 (PR3 + DR_*E_/4)
#define PR5 (PR4 + N_*E_/4)
#define PR6 (PR5 + N_*E_/4)
#define PR7 (PR6 + 32*E_/4)
#define PR8 (PR7 + 4*E_/4)       // conv_w [E][4] -> cwT [4][E] f32
__global__ __launch_bounds__(256) void prep_k(const float* __restrict__ in_w,
                                              const float* __restrict__ skip_w,
                                              const float* __restrict__ out_w,
                                              const float* __restrict__ wd2,
                                              const float* __restrict__ wd1,
                                              const float* __restrict__ wB,
                                              const float* __restrict__ wC,
                                              const float* __restrict__ conv_w,
                                              ushort* __restrict__ wis,
                                              ushort* __restrict__ wo,
                                              ushort* __restrict__ wd2b,
                                              ushort* __restrict__ W96,
                                              float* __restrict__ cwT){
    int i = blockIdx.x * 256 + threadIdx.x;
    const float* src; ushort* dst; int off;
    if (i < PR0)      { src = in_w;   dst = wis;                       off = i; }
    else if (i < PR1) { src = skip_w; dst = wis + (size_t)E_*D_;       off = i - PR0; }
    else if (i < PR2) { src = out_w;  dst = wo;                        off = i - PR1; }
    else if (i < PR3) { src = wd2;    dst = wd2b;                      off = i - PR2; }
    else if (i < PR4) { src = wd1;    dst = W96;                       off = i - PR3; }
    else if (i < PR5) { src = wB;     dst = W96 + (size_t)64*E_;       off = i - PR4; }
    else if (i < PR6) { src = wC;     dst = W96 + (size_t)80*E_;       off = i - PR5; }
    else if (i < PR7) {
        ushort4 z = {0,0,0,0};
        ((ushort4*)(W96 + (size_t)96*E_))[i - PR6] = z;
        return;
    } else if (i < PR8) {
        int u = i - PR7;
        int k = u >> 9;            // tap
        int g = u & 511;           // e-quad
        float4 o;
        o.x = conv_w[(g*4 + 0)*4 + k];
        o.y = conv_w[(g*4 + 1)*4 + k];
        o.z = conv_w[(g*4 + 2)*4 + k];
        o.w = conv_w[(g*4 + 3)*4 + k];
        ((float4*)(cwT + (size_t)k * E_))[g] = o;
        return;
    } else return;
    float4 v = ((const float4*)src)[off];
    ushort4 o;
    o.x = f2bf(v.x); o.y = f2bf(v.y); o.z = f2bf(v.z); o.w = f2bf(v.w);
    ((ushort4*)dst)[off] = o;
}

// ---------------- RMSNorm -> bf16 ----------------
__global__ __launch_bounds__(256) void rmsnorm_k(const float* __restrict__ resid,
                                                 const float* __restrict__ norm_w,
                                                 ushort* __restrict__ xn){
    int row = blockIdx.x;
    const float4* r = (const float4*)(resid + (size_t)row * D_);
    float4 v = r[threadIdx.x];
    float ss = v.x*v.x + v.y*v.y + v.z*v.z + v.w*v.w;
    for (int m = 32; m; m >>= 1) ss += __shfl_xor(ss, m);
    __shared__ float sred[4];
    if ((threadIdx.x & 63) == 0) sred[threadIdx.x >> 6] = ss;
    __syncthreads();
    float tot = sred[0] + sred[1] + sred[2] + sred[3];
    float scale = rsqrtf(tot / (float)D_ + 1e-5f);
    const float4* wv = (const float4*)norm_w;
    float4 w = wv[threadIdx.x];
    ushort4 o;
    o.x = f2bf(v.x * scale * w.x);
    o.y = f2bf(v.y * scale * w.y);
    o.z = f2bf(v.z * scale * w.z);
    o.w = f2bf(v.w * scale * w.w);
    ((ushort4*)(xn + (size_t)row * D_))[threadIdx.x] = o;
}

// ---------------- GEMM machinery ----------------
// r19 XOR swizzle (conflicts -> 0). r20 dbuf + 2D XCD chunk (FETCH 72->33MB).
// r22: dual uses 512-thread blocks (8 waves of 32x64) -- same 128x128 tile and
// 64KB dbuf LDS, but 16 waves/CU resident (was 8): 2x TLP to hide barrier drain.
// [r21 BK=32 regressed: occupancy didn't engage + 4-way conflicts returned.]
#define BM 128
#define BN 128
#define BK 64

__global__ __launch_bounds__(512, 4)
void gemm_dual_k(const ushort* __restrict__ A, const ushort* __restrict__ Bm,
                 ushort* __restrict__ P1, ushort* __restrict__ P2){
    __shared__ __align__(16) ushort As[2][BM * BK];
    __shared__ __align__(16) ushort Bs[2][BN * BK];
    const int xcd = blockIdx.x & 7;
    const int idx = blockIdx.x >> 3;                      // 0..127
    const int row0 = (((xcd >> 2) << 4) + (idx >> 3)) * BM;   // rows 0..31
    const int col0 = (((xcd & 3) << 3) + (idx & 7)) * BN;     // cols 0..31
    const int tid = threadIdx.x;
    const int lane = tid & 63;
    const int wid = tid >> 6;            // 0..7
    const int wm = wid >> 1, wn = wid & 1;   // wave tile 32x64 (4 row-groups x 2 col-groups)
    f32x4 acc[2][4] = {};
    const int l8 = lane >> 3;
    const int cs = ((lane & 7) ^ (l8 & 7)) * 8;   // XOR-swizzled source col

    const int NK = D_ / BK;   // 16
    // stage k=0: 8 waves x 2 iters x 8 rows = 128 rows each of A and B
    #pragma unroll
    for (int i = 0; i < 2; ++i){
        const int R0 = wid * 16 + i * 8;
        gld16(A + (size_t)(row0 + R0 + l8) * D_ + cs, &As[0][R0 * BK]);
        gld16(Bm + (size_t)(col0 + R0 + l8) * D_ + cs, &Bs[0][R0 * BK]);
    }
    __syncthreads();
    int cur = 0;
    for (int ki = 0; ki < NK; ++ki){
        if (ki + 1 < NK){
            const int k0 = (ki + 1) * BK;
            #pragma unroll
            for (int i = 0; i < 2; ++i){
                const int R0 = wid * 16 + i * 8;
                gld16(A + (size_t)(row0 + R0 + l8) * D_ + k0 + cs, &As[cur^1][R0 * BK]);
                gld16(Bm + (size_t)(col0 + R0 + l8) * D_ + k0 + cs, &Bs[cur^1][R0 * BK]);
            }
        }
        #pragma unroll
        for (int kk = 0; kk < 2; ++kk){
            bf16x8 af[2], bfr[4];
            const int krow = lane & 15;
            const int kcol = ((kk * 4 + (lane >> 4)) ^ (krow & 7)) * 8;
            #pragma unroll
            for (int mi = 0; mi < 2; ++mi)
                af[mi] = *(const bf16x8*)(&As[cur][(wm*32 + mi*16 + krow) * BK + kcol]);
            #pragma unroll
            for (int ni = 0; ni < 4; ++ni)
                bfr[ni] = *(const bf16x8*)(&Bs[cur][(wn*64 + ni*16 + krow) * BK + kcol]);
            #pragma unroll
            for (int mi = 0; mi < 2; ++mi)
                #pragma unroll
                for (int ni = 0; ni < 4; ++ni)
                    acc[mi][ni] = __builtin_amdgcn_mfma_f32_16x16x32_bf16(af[mi], bfr[ni], acc[mi][ni], 0, 0, 0);
        }
        __syncthreads();
        cur ^= 1;
    }
    ushort* base = (col0 < E_) ? P1 : P2;
    const int cb = (col0 < E_) ? col0 : col0 - E_;
    #pragma unroll
    for (int mi = 0; mi < 2; ++mi)
        #pragma unroll
        for (int ni = 0; ni < 4; ++ni)
            #pragma unroll
            for (int j = 0; j < 4; ++j){
                int r = row0 + wm*32 + mi*16 + (lane >> 4) * 4 + j;
                int c = cb + wn*64 + ni*16 + (lane & 15);
                base[(size_t)r * E_ + c] = f2bf(acc[mi][ni][j]);
            }
}

// out-proj: BM=64 -> 512 blocks, XCD swizzle, BK=64 dbuf (r20 form)
#define OBM 64
__global__ __launch_bounds__(256)
void gemm_out_k(const ushort* __restrict__ A, const ushort* __restrict__ Bm,
                float* __restrict__ Cp, const float* __restrict__ aux){
    __shared__ __align__(16) ushort As[2][OBM * BK];
    __shared__ __align__(16) ushort Bs[2][BN * BK];
    const int wid9 = (blockIdx.x & 7) * 64 + (blockIdx.x >> 3);  // nwg=512, bijective
    const int col0 = (wid9 & 7) * BN;
    const int row0 = (wid9 >> 3) * OBM;
    const int tid = threadIdx.x;
    const int lane = tid & 63;
    const int wid = tid >> 6;
    const int wm = wid >> 1, wn = wid & 1;   // wave tile 32x64
    f32x4 acc[2][4] = {};
    const int l8 = lane >> 3;
    const int cs = ((lane & 7) ^ (l8 & 7)) * 8;

    const int NK = E_ / BK;   // 32
    #pragma unroll
    for (int i = 0; i < 2; ++i){
        const int R0 = wid * 16 + i * 8;
        gld16(A + (size_t)(row0 + R0 + l8) * E_ + cs, &As[0][R0 * BK]);
    }
    #pragma unroll
    for (int i = 0; i < 4; ++i){
        const int R0 = wid * 32 + i * 8;
        gld16(Bm + (size_t)(col0 + R0 + l8) * E_ + cs, &Bs[0][R0 * BK]);
    }
    __syncthreads();
    int cur = 0;
    for (int ki = 0; ki < NK; ++ki){
        if (ki + 1 < NK){
            const int k0 = (ki + 1) * BK;
            #pragma unroll
            for (int i = 0; i < 2; ++i){
                const int R0 = wid * 16 + i * 8;
                gld16(A + (size_t)(row0 + R0 + l8) * E_ + k0 + cs, &As[cur^1][R0 * BK]);
            }
            #pragma unroll
            for (int i = 0; i < 4; ++i){
                const int R0 = wid * 32 + i * 8;
                gld16(Bm + (size_t)(col0 + R0 + l8) * E_ + k0 + cs, &Bs[cur^1][R0 * BK]);
            }
        }
        #pragma unroll
        for (int kk = 0; kk < 2; ++kk){
            bf16x8 af[2], bfr[4];
            const int krow = lane & 15;
            const int kcol = ((kk * 4 + (lane >> 4)) ^ (krow & 7)) * 8;
            #pragma unroll
            for (int mi = 0; mi < 2; ++mi)
                af[mi] = *(const bf16x8*)(&As[cur][(wm*32 + mi*16 + krow) * BK + kcol]);
            #pragma unroll
            for (int ni = 0; ni < 4; ++ni)
                bfr[ni] = *(const bf16x8*)(&Bs[cur][(wn*64 + ni*16 + krow) * BK + kcol]);
            #pragma unroll
            for (int mi = 0; mi < 2; ++mi)
                #pragma unroll
                for (int ni = 0; ni < 4; ++ni)
                    acc[mi][ni] = __builtin_amdgcn_mfma_f32_16x16x32_bf16(af[mi], bfr[ni], acc[mi][ni], 0, 0, 0);
        }
        __syncthreads();
        cur ^= 1;
    }
    #pragma unroll
    for (int mi = 0; mi < 2; ++mi)
        #pragma unroll
        for (int ni = 0; ni < 4; ++ni)
            #pragma unroll
            for (int j = 0; j < 4; ++j){
                int r = row0 + wm*32 + mi*16 + (lane >> 4) * 4 + j;
                int c = col0 + wn*64 + ni*16 + (lane & 15);
                size_t idx = (size_t)r * D_ + c;
                Cp[idx] = acc[mi][ni][j] + aux[idx];
            }
}

// ---------------- C96 GEMM, split-K, CBM=64 ----------------
#define CBM 64
__global__ __launch_bounds__(256)
void gemm_c96_sk(const ushort* __restrict__ A, const ushort* __restrict__ Bm,
                 float* __restrict__ part){
    __shared__ __align__(16) ushort As[CBM * BK];
    __shared__ __align__(16) ushort Bs[128 * BK];
    const int ks = blockIdx.x;
    const int row0 = blockIdx.y * CBM;
    const int tid = threadIdx.x;
    const int lane = tid & 63;
    const int wid = tid >> 6;
    const int wm = wid >> 1, wn = wid & 1;   // wave tile 32x64
    f32x4 acc[2][4] = {};
    const int l8 = lane >> 3;
    const int cs = ((lane & 7) ^ (l8 & 7)) * 8;

    for (int k0 = ks * (E_ / KS_); k0 < (ks + 1) * (E_ / KS_); k0 += BK){
        #pragma unroll
        for (int i = 0; i < 2; ++i){
            const int R0 = wid * 16 + i * 8;
            gld16(A + (size_t)(row0 + R0 + l8) * E_ + k0 + cs, As + R0 * BK);
        }
        #pragma unroll
        for (int i = 0; i < 4; ++i){
            const int R0 = wid * 32 + i * 8;
            gld16(Bm + (size_t)(R0 + l8) * E_ + k0 + cs, Bs + R0 * BK);
        }
        __syncthreads();
        #pragma unroll
        for (int kk = 0; kk < 2; ++kk){
            bf16x8 af[2], bfr[4];
            const int krow = lane & 15;
            const int kcol = ((kk * 4 + (lane >> 4)) ^ (krow & 7)) * 8;
            #pragma unroll
            for (int mi = 0; mi < 2; ++mi)
                af[mi] = *(const bf16x8*)(As + (wm*32 + mi*16 + krow) * BK + kcol);
            #pragma unroll
            for (int ni = 0; ni < 4; ++ni)
                bfr[ni] = *(const bf16x8*)(Bs + (wn*64 + ni*16 + krow) * BK + kcol);
            #pragma unroll
            for (int mi = 0; mi < 2; ++mi)
                #pragma unroll
                for (int ni = 0; ni < 4; ++ni)
                    acc[mi][ni] = __builtin_amdgcn_mfma_f32_16x16x32_bf16(af[mi], bfr[ni], acc[mi][ni], 0, 0, 0);
        }
        __syncthreads();
    }
    float* dst = part + (size_t)ks * M_ * 128;
    #pragma unroll
    for (int mi = 0; mi < 2; ++mi)
        #pragma unroll
        for (int ni = 0; ni < 4; ++ni)
            #pragma unroll
            for (int j = 0; j < 4; ++j){
                int r = row0 + wm*32 + mi*16 + (lane >> 4) * 4 + j;
                int c = wn*64 + ni*16 + (lane & 15);
                dst[(size_t)r * 128 + c] = acc[mi][ni][j];
            }
}

__global__ __launch_bounds__(256) void c96_reduce_k(const float* __restrict__ part,
                                                    ushort* __restrict__ C96){
    int i4 = blockIdx.x * 256 + threadIdx.x;     // over M_*128/4
    float4 a = *(const float4*)(part + (size_t)i4 * 4);
    #pragma unroll
    for (int k = 1; k < KS_; ++k){
        float4 b = *(const float4*)(part + (size_t)k * M_ * 128 + (size_t)i4 * 4);
        a.x += b.x; a.y += b.y; a.z += b.z; a.w += b.w;
    }
    ushort4 o;
    o.x = f2bf(a.x); o.y = f2bf(a.y); o.z = f2bf(a.z); o.w = f2bf(a.w);
    *(ushort4*)(C96 + (size_t)i4 * 4) = o;
}

// ---------------- causal depthwise conv1d + silu -> bf16 (coalesced taps) ----------------
__global__ __launch_bounds__(256) void conv_silu_k(const ushort* __restrict__ xpre,
                                                   const float* __restrict__ cwT,
                                                   const float* __restrict__ conv_b,
                                                   ushort* __restrict__ xb){
    int i4 = blockIdx.x * 256 + threadIdx.x;
    if (i4 >= M_ * E_ / 4) return;
    int idx = i4 * 4;
    int e = idx & (E_ - 1);
    int bl = idx >> 11;
    int t = bl & (L_ - 1);
    float4 b4 = *(const float4*)(conv_b + e);
    float a0 = b4.x, a1 = b4.y, a2 = b4.z, a3 = b4.w;
    #pragma unroll
    for (int k = 0; k < 4; ++k){
        int dt = 3 - k;
        if (t >= dt){
            ushort4 xv = *(const ushort4*)(xpre + idx - dt * E_);
            float4 wv = *(const float4*)(cwT + (size_t)k * E_ + e);
            a0 += bf2f(xv.x) * wv.x;
            a1 += bf2f(xv.y) * wv.y;
            a2 += bf2f(xv.z) * wv.z;
            a3 += bf2f(xv.w) * wv.w;
        }
    }
    ushort4 sb;
    sb.x = f2bf(fast_silu(a0));
    sb.y = f2bf(fast_silu(a1));
    sb.z = f2bf(fast_silu(a2));
    sb.w = f2bf(fast_silu(a3));
    *(ushort4*)(xb + idx) = sb;
}

// ---------------- chunk-parallel selective scan, delta fused via MFMA ----------------
#define SF2 36   // f32 tile stride (144B, 16B-aligned)
#define SYD 20   // sy stride

__device__ __forceinline__ void seg_swz(int& b, int& s, int& e0){
    int lin = blockIdx.x + 128 * (blockIdx.y + 16 * blockIdx.z);   // nwg = 4096
    int swz = (lin & 7) * 512 + (lin >> 3);                        // bijective
    e0 = (swz & 127) * 16;
    s  = (swz >> 7) & 15;
    b  = swz >> 11;
}

// grid (E_/16, SSEG, B_), block 256 = 16 e x 16 n
__global__ __launch_bounds__(256, 8) void seg1_k(const ushort* __restrict__ xb,
                                              const ushort* __restrict__ C96,
                                              const ushort* __restrict__ wd2b,
                                              const float* __restrict__ wd2_bias,
                                              const float* __restrict__ A_log,
                                              float* __restrict__ F,
                                              float* __restrict__ segdt){
    int b, s, e0; seg_swz(b, s, e0);
    const int tid = threadIdx.x;
    const int lane = tid & 63, wid = tid >> 6;
    const int n = tid & 15, ei = tid >> 4;
    const int e = e0 + ei;
    const float Aen2 = -__expf(A_log[e * N_ + n]) * LOG2E;
    float h = 0.f;
    __shared__ __align__(16) ushort sxr[CH][72];
    __shared__ __align__(16) ushort swd2[16][72];
    __shared__ __align__(16) ushort sxu[16][40];
    __shared__ float sd[16][SF2], sdx[16][SF2], sB[16][SF2];
    __shared__ float ssdt[2][16];
    const int tq = tid >> 3, qc = tid & 7;   // row 0..31, col-group 0..7

    if (tid < 128){
        int r = tid >> 3, cc = (tid & 7) * 8;
        *(uint4*)&swd2[r][cc] = *(const uint4*)(wd2b + (size_t)(e0 + r) * DR_ + cc);
    }
    const float bias = wd2_bias[e0 + (lane & 15)];
    float psdt = 0.f;   // producer-lane partial sum of delta over its t-slice

    for (int c = 0; c < LSEG / CH; ++c){
        int t0 = s * LSEG + c * CH;
        size_t row = (size_t)(b * L_ + t0 + tq);
        *(uint4*)&sxr[tq][qc * 8] = *(const uint4*)(C96 + row * 128 + qc * 8);
        ushort2 rB = *(const ushort2*)(C96 + row * 128 + 64 + qc * 2);
        ushort2 xu = *(const ushort2*)(xb + row * E_ + e0 + qc * 2);
        sB[qc*2+0][tq] = bf2f(rB.x); sB[qc*2+1][tq] = bf2f(rB.y);
        sxu[qc*2+0][tq] = xu.x; sxu[qc*2+1][tq] = xu.y;
        __syncthreads();
        // fused delta: waves 0,1 each compute one 16-t x 16-e tile
        if (wid < 2){
            f32x4 dacc = {};
            #pragma unroll
            for (int kk = 0; kk < 2; ++kk){
                bf16x8 af = *(const bf16x8*)&sxr[wid*16 + (lane & 15)][kk*32 + (lane >> 4)*8];
                bf16x8 bf = *(const bf16x8*)&swd2[lane & 15][kk*32 + (lane >> 4)*8];
                dacc = __builtin_amdgcn_mfma_f32_16x16x32_bf16(af, bf, dacc, 0, 0, 0);
            }
            const int crow = lane & 15;
            const int ttc = wid*16 + (lane >> 4)*4;
            float4 dv;
            dv.x = softplus_f(dacc[0] + bias);
            dv.y = softplus_f(dacc[1] + bias);
            dv.z = softplus_f(dacc[2] + bias);
            dv.w = softplus_f(dacc[3] + bias);
            *(float4*)&sd[crow][ttc] = dv;
            psdt += dv.x + dv.y + dv.z + dv.w;
            ushort4 xu4 = *(const ushort4*)&sxu[crow][ttc];
            float4 dxv;
            dxv.x = dv.x * bf2f(xu4.x); dxv.y = dv.y * bf2f(xu4.y);
            dxv.z = dv.z * bf2f(xu4.z); dxv.w = dv.w * bf2f(xu4.w);
            *(float4*)&sdx[crow][ttc] = dxv;
        }
        __syncthreads();
        #pragma unroll
        for (int t = 0; t < CH; t += 4){
            float4 d4  = *(const float4*)&sd[ei][t];
            float4 dx4 = *(const float4*)&sdx[ei][t];
            float4 b4  = *(const float4*)&sB[n][t];
            h = fexp2(d4.x*Aen2)*h + dx4.x*b4.x;
            h = fexp2(d4.y*Aen2)*h + dx4.y*b4.y;
            h = fexp2(d4.z*Aen2)*h + dx4.z*b4.z;
            h = fexp2(d4.w*Aen2)*h + dx4.w*b4.w;
        }
        __syncthreads();
    }
    // producer-lane sdt reduce
    if (wid < 2){
        psdt += __shfl_xor(psdt, 16);
        psdt += __shfl_xor(psdt, 32);
        if (lane < 16) ssdt[wid][lane] = psdt;
    }
    size_t base = ((size_t)(b * SSEG + s) * E_ + e) * N_ + n;
    F[base] = h;
    __syncthreads();
    if (tid < 16)
        segdt[(size_t)(b * SSEG + s) * E_ + e0 + tid] = ssdt[0][tid] + ssdt[1][tid];
}

// sequential carry over SSEG segments per (b,e,n)
__global__ __launch_bounds__(256) void carry_k(const float* __restrict__ F,
                                               const float* __restrict__ segdt,
                                               const float* __restrict__ A_log,
                                               float* __restrict__ carr){
    int idx = blockIdx.x * 256 + threadIdx.x;
    int n = idx & 15;
    int e = (idx >> 4) & (E_ - 1);
    int b = idx >> 15;
    const float Aen2 = -__expf(A_log[e * N_ + n]) * LOG2E;
    float c = 0.f;
    #pragma unroll
    for (int s = 0; s < SSEG; ++s){
        size_t base = ((size_t)(b * SSEG + s) * E_ + e) * N_ + n;
        carr[base] = c;
        float P = fexp2(Aen2 * segdt[(size_t)(b * SSEG + s) * E_ + e]);
        c = P * c + F[base];
    }
}

// grid (E_/16, SSEG, B_), block 256; gate fused into store
__global__ __launch_bounds__(256, 8) void seg2_k(const ushort* __restrict__ xb,
                                              const ushort* __restrict__ C96,
                                              const ushort* __restrict__ wd2b,
                                              const float* __restrict__ wd2_bias,
                                              const float* __restrict__ A_log,
                                              const float* __restrict__ carr,
                                              const ushort* __restrict__ skipb,
                                              const float* __restrict__ W_D,
                                              ushort* __restrict__ y2){
    int b, s, e0; seg_swz(b, s, e0);
    const int tid = threadIdx.x;
    const int lane = tid & 63, wid = tid >> 6;
    const int n = tid & 15, ei = tid >> 4;
    const int e = e0 + ei;
    const float Aen2 = -__expf(A_log[e * N_ + n]) * LOG2E;
    float h = carr[((size_t)(b * SSEG + s) * E_ + e) * N_ + n];
    __shared__ __align__(16) ushort sxr[CH][72];
    __shared__ __align__(16) ushort swd2[16][72];
    __shared__ __align__(16) ushort sxu[16][40];
    __shared__ float sd[16][SF2], sdx[16][SF2], sB[16][SF2], sC[16][SF2];
    __shared__ float sy[CH][SYD];
    const int tq = tid >> 3, qc = tid & 7;

    if (tid < 128){
        int r = tid >> 3, cc = (tid & 7) * 8;
        *(uint4*)&swd2[r][cc] = *(const uint4*)(wd2b + (size_t)(e0 + r) * DR_ + cc);
    }
    const float bias = wd2_bias[e0 + (lane & 15)];
    const float wv0 = W_D[e0 + qc * 2], wv1 = W_D[e0 + qc * 2 + 1];

    for (int c = 0; c < LSEG / CH; ++c){
        int t0 = s * LSEG + c * CH;
        size_t row = (size_t)(b * L_ + t0 + tq);
        *(uint4*)&sxr[tq][qc * 8] = *(const uint4*)(C96 + row * 128 + qc * 8);
        ushort2 rB = *(const ushort2*)(C96 + row * 128 + 64 + qc * 2);
        ushort2 rC = *(const ushort2*)(C96 + row * 128 + 80 + qc * 2);
        ushort2 xu = *(const ushort2*)(xb + row * E_ + e0 + qc * 2);
        ushort2 sv_pre = *(const ushort2*)(skipb + row * E_ + e0 + qc * 2);  // gate prefetch
        sB[qc*2+0][tq] = bf2f(rB.x); sB[qc*2+1][tq] = bf2f(rB.y);
        sC[qc*2+0][tq] = bf2f(rC.x); sC[qc*2+1][tq] = bf2f(rC.y);
        sxu[qc*2+0][tq] = xu.x; sxu[qc*2+1][tq] = xu.y;
        __syncthreads();
        if (wid < 2){
            f32x4 dacc = {};
            #pragma unroll
            for (int kk = 0; kk < 2; ++kk){
                bf16x8 af = *(const bf16x8*)&sxr[wid*16 + (lane & 15)][kk*32 + (lane >> 4)*8];
                bf16x8 bf = *(const bf16x8*)&swd2[lane & 15][kk*32 + (lane >> 4)*8];
                dacc = __builtin_amdgcn_mfma_f32_16x16x32_bf16(af, bf, dacc, 0, 0, 0);
            }
            const int crow = lane & 15;
            const int ttc = wid*16 + (lane >> 4)*4;
            float4 dv;
            dv.x = softplus_f(dacc[0] + bias);
            dv.y = softplus_f(dacc[1] + bias);
            dv.z = softplus_f(dacc[2] + bias);
            dv.w = softplus_f(dacc[3] + bias);
            *(float4*)&sd[crow][ttc] = dv;
            ushort4 xu4 = *(const ushort4*)&sxu[crow][ttc];
            float4 dxv;
            dxv.x = dv.x * bf2f(xu4.x); dxv.y = dv.y * bf2f(xu4.y);
            dxv.z = dv.z * bf2f(xu4.z); dxv.w = dv.w * bf2f(xu4.w);
            *(float4*)&sdx[crow][ttc] = dxv;
        }
        __syncthreads();
        #pragma unroll
        for (int t = 0; t < CH; t += 4){
            float4 d4  = *(const float4*)&sd[ei][t];
            float4 dx4 = *(const float4*)&sdx[ei][t];
            float4 b4  = *(const float4*)&sB[n][t];
            float4 c4  = *(const float4*)&sC[n][t];
            float y0, y1, y2v, y3;
            h = fexp2(d4.x*Aen2)*h + dx4.x*b4.x;  y0 = h * c4.x;
            h = fexp2(d4.y*Aen2)*h + dx4.y*b4.y;  y1 = h * c4.y;
            h = fexp2(d4.z*Aen2)*h + dx4.z*b4.z;  y2v = h * c4.z;
            h = fexp2(d4.w*Aen2)*h + dx4.w*b4.w;  y3 = h * c4.w;
            // 4-value 16-lane reduce via DPP (zero DS), bit-identical to xor butterfly
            float s01 = (n & 1) ? y0 : y1;
            float r01 = DPP_F(s01, 0xB1);        // quad_perm [1,0,3,2] == xor1
            float s23 = (n & 1) ? y2v : y3;
            float r23 = DPP_F(s23, 0xB1);
            float va, vb;
            if (n & 1){ va = y1 + r01; vb = y3 + r23; }
            else      { va = y0 + r01; vb = y2v + r23; }
            float s2 = (n & 2) ? va : vb;
            float r2 = DPP_F(s2, 0x4E);          // quad_perm [2,3,0,1] == xor2
            float v = ((n & 2) ? vb : va) + r2;
            v += DPP_F(v, 0x124);                // row_ror:4  (xor4-equivalent sum)
            v += DPP_F(v, 0x128);                // row_ror:8  (xor8-equivalent sum)
            if (n < 4) sy[t + n][ei] = v;
        }
        __syncthreads();
        {
            // fused gate: y2 = (y + W_D*x) * silu(skip) -> bf16 (skip prefetched)
            size_t orow = (size_t)(b * L_ + t0 + tq);
            float yv0 = sy[tq][qc*2], yv1 = sy[tq][qc*2+1];
            float xs0 = bf2f(sxu[qc*2+0][tq]), xs1 = bf2f(sxu[qc*2+1][tq]);
            float sk0 = bf2f(sv_pre.x), sk1 = bf2f(sv_pre.y);
            ushort2 o;
            o.x = f2bf((yv0 + wv0 * xs0) * fast_silu(sk0));
            o.y = f2bf((yv1 + wv1 * xs1) * fast_silu(sk1));
            *(ushort2*)(y2 + orow * E_ + e0 + qc * 2) = o;
        }
        __syncthreads();
    }
}

// ---------------- launch ----------------
extern "C" void kernel_launch(void* const* d_in, const int* in_sizes, int n_in,
                              void* d_out, int out_size, void* d_ws, size_t ws_size,
                              hipStream_t stream){
    const float* resid  = (const float*)d_in[0];
    const float* norm_w = (const float*)d_in[1];
    const float* skip_w = (const float*)d_in[2];
    const float* in_w   = (const float*)d_in[3];
    const float* conv_w = (const float*)d_in[4];
    const float* conv_b = (const float*)d_in[5];
    const float* wd1    = (const float*)d_in[6];
    const float* wd2    = (const float*)d_in[7];
    const float* wd2_b  = (const float*)d_in[8];
    const float* wB     = (const float*)d_in[9];
    const float* wC     = (const float*)d_in[10];
    const float* A_log  = (const float*)d_in[11];
    const float* W_D    = (const float*)d_in[12];
    const float* out_w  = (const float*)d_in[13];
    float* out = (float*)d_out;

    char* ws = (char*)d_ws;
    size_t off = 0;
    auto alloc = [&](size_t bytes) -> char* {
        char* p = ws + off;
        off += (bytes + 255) & ~(size_t)255;
        return p;
    };
    char* alias_base = ws;
    ushort* wis_b   = (ushort*)alloc((size_t)2 * E_ * D_ * 2);  // 8MB stacked [in_w; skip_w]
    ushort* xn_b    = (ushort*)alloc((size_t)M_ * D_ * 2);      // 8MB
    ushort* xpre_b  = (ushort*)alloc((size_t)M_ * E_ * 2);      // 16MB
    float*  part_buf= (float*)alias_base;                       // 16MB alias (KS_*M_*128*4)
    ushort* wo_b    = (ushort*)alloc((size_t)D_ * E_ * 2);       // 4MB
    ushort* wd2_bf  = (ushort*)alloc((size_t)E_ * DR_ * 2);      // 256KB
    ushort* W96_b   = (ushort*)alloc((size_t)128 * E_ * 2);      // 512KB
    float*  cwT_b   = (float*)alloc((size_t)4 * E_ * 4);         // 32KB transposed taps
    ushort* skip_b  = (ushort*)alloc((size_t)M_ * E_ * 2);       // 16MB
    ushort* xb_b    = (ushort*)alloc((size_t)M_ * E_ * 2);       // 16MB
    ushort* C96_b   = (ushort*)alloc((size_t)M_ * 128 * 2);      // 1MB
    float*  scr     = (float*)alloc((size_t)9 * 1024 * 1024);    // 9MB scratch
    ushort* y2_b    = (ushort*)alloc((size_t)M_ * E_ * 2);       // 16MB
    float* F_buf    = scr;
    float* carr_buf = scr + (size_t)B_ * SSEG * E_ * N_;
    float* segdt_buf= scr + (size_t)2 * B_ * SSEG * E_ * N_;
    (void)ws_size; (void)in_sizes; (void)n_in; (void)out_size;

    const int thr = 256;

    prep_k<<<(PR8 + 255)/256, thr, 0, stream>>>(in_w, skip_w, out_w, wd2, wd1, wB, wC, conv_w,
                                                wis_b, wo_b, wd2_bf, W96_b, cwT_b);

    rmsnorm_k<<<M_, thr, 0, stream>>>(resid, norm_w, xn_b);

    gemm_dual_k<<<1024, 512, 0, stream>>>(xn_b, wis_b, xpre_b, skip_b);

    conv_silu_k<<<(M_*E_/4 + 255)/256, thr, 0, stream>>>(xpre_b, cwT_b, conv_b, xb_b);

    gemm_c96_sk<<<dim3(KS_, M_/CBM), thr, 0, stream>>>(xb_b, W96_b, part_buf);
    c96_reduce_k<<<(M_*128/4)/256, thr, 0, stream>>>(part_buf, C96_b);

    seg1_k<<<dim3(E_/16, SSEG, B_), thr, 0, stream>>>(xb_b, C96_b, wd2_bf, wd2_b, A_log, F_buf, segdt_buf);
    carry_k<<<(B_*E_*N_)/256, thr, 0, stream>>>(F_buf, segdt_buf, A_log, carr_buf);
    seg2_k<<<dim3(E_/16, SSEG, B_), thr, 0, stream>>>(xb_b, C96_b, wd2_bf, wd2_b, A_log, carr_buf,
                                                      skip_b, W_D, y2_b);

    gemm_out_k<<<512, thr, 0, stream>>>(y2_b, wo_b, out, resid);
}

// Round 23
// 191.106 us; speedup vs baseline: 1.1010x; 1.0189x over previous
//
#include <hip/hip_runtime.h>
#include <hip/hip_bf16.h>

// Problem dims (fixed)
#define B_ 2
#define L_ 2048
#define D_ 1024
#define E_ 2048
#define N_ 16
#define DR_ 64
#define DC_ 4
#define M_ (B_*L_)   // 4096 rows
#define SSEG 16      // scan segments
#define LSEG (L_/SSEG)  // 128
#define KS_ 8        // split-K factor for C96 GEMM
#define CH 32        // scan chunk (timesteps per barrier group)
#define LOG2E 1.4426950408889634f

typedef __attribute__((ext_vector_type(8))) short bf16x8;
typedef __attribute__((ext_vector_type(4))) float f32x4;

__device__ __forceinline__ ushort f2bf(float x){
    union { float f; unsigned u; } v; v.f = x;
    unsigned r = v.u + 0x7FFFu + ((v.u >> 16) & 1u);
    return (ushort)(r >> 16);
}
__device__ __forceinline__ float bf2f(ushort u){
    union { unsigned u; float f; } v; v.u = ((unsigned)u) << 16;
    return v.f;
}
// single v_exp_f32 (2^x)
__device__ __forceinline__ float fexp2(float x){
    float r;
    asm("v_exp_f32 %0, %1" : "=v"(r) : "v"(x));
    return r;
}
// fast silu via v_rcp_f32
__device__ __forceinline__ float fast_silu(float x){
    return x * __builtin_amdgcn_rcpf(1.f + __expf(-x));
}
// fast softplus
__device__ __forceinline__ float softplus_f(float z){
    return (z > 20.f) ? z : __logf(1.f + __expf(z));
}

// DPP cross-lane (VALU, zero DS traffic)
#define DPP_F(x, CTRL) __int_as_float(__builtin_amdgcn_update_dpp(0, __float_as_int(x), (CTRL), 0xf, 0xf, true))

// async global->LDS, 16B per lane
__device__ __forceinline__ void gld16(const void* g, void* l){
    __builtin_amdgcn_global_load_lds(
        (const __attribute__((address_space(1))) unsigned int*)g,
        (__attribute__((address_space(3))) unsigned int*)l,
        16, 0, 0);
}

// ---------------- fused weight prep (+ conv_w transpose) ----------------
#define PR0 (E_*D_/4)
#define PR1 (2*PR0)
#define PR2 (3*PR0)
#define PR3 (PR2 + E_*DR_/4)
#define PR4 (PR3 + DR_*E_/4)
#define PR5 (PR4 + N_*E_/4)
#define PR6 (PR5 + N_*E_/4)
#define PR7 (PR6 + 32*E_/4)
#define PR8 (PR7 + 4*E_/4)       // conv_w [E][4] -> cwT [4][E] f32
__global__ __launch_bounds__(256) void prep_k(const float* __restrict__ in_w,
                                              const float* __restrict__ skip_w,
                                              const float* __restrict__ out_w,
                                              const float* __restrict__ wd2,
                                              const float* __restrict__ wd1,
                                              const float* __restrict__ wB,
                                              const float* __restrict__ wC,
                                              const float* __restrict__ conv_w,
                                              ushort* __restrict__ wis,
                                              ushort* __restrict__ wo,
                                              ushort* __restrict__ wd2b,
                                              ushort* __restrict__ W96,
                                              float* __restrict__ cwT){
    int i = blockIdx.x * 256 + threadIdx.x;
    const float* src; ushort* dst; int off;
    if (i < PR0)      { src = in_w;   dst = wis;                       off = i; }
    else if (i < PR1) { src = skip_w; dst = wis + (size_t)E_*D_;       off = i - PR0; }
    else if (i < PR2) { src = out_w;  dst = wo;                        off = i - PR1; }
    else if (i < PR3) { src = wd2;    dst = wd2b;                      off = i - PR2; }
    else if (i < PR4) { src = wd1;    dst = W96;                       off = i - PR3; }
    else if (i < PR5) { src = wB;     dst = W96 + (size_t)64*E_;       off = i - PR4; }
    else if (i < PR6) { src = wC;     dst = W96 + (size_t)80*E_;       off = i - PR5; }
    else if (i < PR7) {
        ushort4 z = {0,0,0,0};
        ((ushort4*)(W96 + (size_t)96*E_))[i - PR6] = z;
        return;
    } else if (i < PR8) {
        int u = i - PR7;
        int k = u >> 9;            // tap
        int g = u & 511;           // e-quad
        float4 o;
        o.x = conv_w[(g*4 + 0)*4 + k];
        o.y = conv_w[(g*4 + 1)*4 + k];
        o.z = conv_w[(g*4 + 2)*4 + k];
        o.w = conv_w[(g*4 + 3)*4 + k];
        ((float4*)(cwT + (size_t)k * E_))[g] = o;
        return;
    } else return;
    float4 v = ((const float4*)src)[off];
    ushort4 o;
    o.x = f2bf(v.x); o.y = f2bf(v.y); o.z = f2bf(v.z); o.w = f2bf(v.w);
    ((ushort4*)dst)[off] = o;
}

// ---------------- RMSNorm -> bf16 ----------------
__global__ __launch_bounds__(256) void rmsnorm_k(const float* __restrict__ resid,
                                                 const float* __restrict__ norm_w,
                                                 ushort* __restrict__ xn){
    int row = blockIdx.x;
    const float4* r = (const float4*)(resid + (size_t)row * D_);
    float4 v = r[threadIdx.x];
    float ss = v.x*v.x + v.y*v.y + v.z*v.z + v.w*v.w;
    for (int m = 32; m; m >>= 1) ss += __shfl_xor(ss, m);
    __shared__ float sred[4];
    if ((threadIdx.x & 63) == 0) sred[threadIdx.x >> 6] = ss;
    __syncthreads();
    float tot = sred[0] + sred[1] + sred[2] + sred[3];
    float scale = rsqrtf(tot / (float)D_ + 1e-5f);
    const float4* wv = (const float4*)norm_w;
    float4 w = wv[threadIdx.x];
    ushort4 o;
    o.x = f2bf(v.x * scale * w.x);
    o.y = f2bf(v.y * scale * w.y);
    o.z = f2bf(v.z * scale * w.z);
    o.w = f2bf(v.w * scale * w.w);
    ((ushort4*)(xn + (size_t)row * D_))[threadIdx.x] = o;
}

// ---------------- GEMM machinery ----------------
// r19 XOR swizzle (conflicts -> 0). r20 dbuf + 2D XCD chunk. r22: 512-thread dual
// (16 waves/CU) recovered the latency-bound stall. r23: same 512-thread treatment
// for gemm_out and gemm_c96_sk (wave tile 16x64, 8 waves as 4x2).
#define BM 128
#define BN 128
#define BK 64

__global__ __launch_bounds__(512, 4)
void gemm_dual_k(const ushort* __restrict__ A, const ushort* __restrict__ Bm,
                 ushort* __restrict__ P1, ushort* __restrict__ P2){
    __shared__ __align__(16) ushort As[2][BM * BK];
    __shared__ __align__(16) ushort Bs[2][BN * BK];
    const int xcd = blockIdx.x & 7;
    const int idx = blockIdx.x >> 3;                      // 0..127
    const int row0 = (((xcd >> 2) << 4) + (idx >> 3)) * BM;   // rows 0..31
    const int col0 = (((xcd & 3) << 3) + (idx & 7)) * BN;     // cols 0..31
    const int tid = threadIdx.x;
    const int lane = tid & 63;
    const int wid = tid >> 6;            // 0..7
    const int wm = wid >> 1, wn = wid & 1;   // wave tile 32x64
    f32x4 acc[2][4] = {};
    const int l8 = lane >> 3;
    const int cs = ((lane & 7) ^ (l8 & 7)) * 8;   // XOR-swizzled source col

    const int NK = D_ / BK;   // 16
    #pragma unroll
    for (int i = 0; i < 2; ++i){
        const int R0 = wid * 16 + i * 8;
        gld16(A + (size_t)(row0 + R0 + l8) * D_ + cs, &As[0][R0 * BK]);
        gld16(Bm + (size_t)(col0 + R0 + l8) * D_ + cs, &Bs[0][R0 * BK]);
    }
    __syncthreads();
    int cur = 0;
    for (int ki = 0; ki < NK; ++ki){
        if (ki + 1 < NK){
            const int k0 = (ki + 1) * BK;
            #pragma unroll
            for (int i = 0; i < 2; ++i){
                const int R0 = wid * 16 + i * 8;
                gld16(A + (size_t)(row0 + R0 + l8) * D_ + k0 + cs, &As[cur^1][R0 * BK]);
                gld16(Bm + (size_t)(col0 + R0 + l8) * D_ + k0 + cs, &Bs[cur^1][R0 * BK]);
            }
        }
        #pragma unroll
        for (int kk = 0; kk < 2; ++kk){
            bf16x8 af[2], bfr[4];
            const int krow = lane & 15;
            const int kcol = ((kk * 4 + (lane >> 4)) ^ (krow & 7)) * 8;
            #pragma unroll
            for (int mi = 0; mi < 2; ++mi)
                af[mi] = *(const bf16x8*)(&As[cur][(wm*32 + mi*16 + krow) * BK + kcol]);
            #pragma unroll
            for (int ni = 0; ni < 4; ++ni)
                bfr[ni] = *(const bf16x8*)(&Bs[cur][(wn*64 + ni*16 + krow) * BK + kcol]);
            #pragma unroll
            for (int mi = 0; mi < 2; ++mi)
                #pragma unroll
                for (int ni = 0; ni < 4; ++ni)
                    acc[mi][ni] = __builtin_amdgcn_mfma_f32_16x16x32_bf16(af[mi], bfr[ni], acc[mi][ni], 0, 0, 0);
        }
        __syncthreads();
        cur ^= 1;
    }
    ushort* base = (col0 < E_) ? P1 : P2;
    const int cb = (col0 < E_) ? col0 : col0 - E_;
    #pragma unroll
    for (int mi = 0; mi < 2; ++mi)
        #pragma unroll
        for (int ni = 0; ni < 4; ++ni)
            #pragma unroll
            for (int j = 0; j < 4; ++j){
                int r = row0 + wm*32 + mi*16 + (lane >> 4) * 4 + j;
                int c = cb + wn*64 + ni*16 + (lane & 15);
                base[(size_t)r * E_ + c] = f2bf(acc[mi][ni][j]);
            }
}

// out-proj: BM=64 -> 512 blocks, XCD swizzle, BK=64 dbuf, 512 threads (r23)
#define OBM 64
__global__ __launch_bounds__(512, 4)
void gemm_out_k(const ushort* __restrict__ A, const ushort* __restrict__ Bm,
                float* __restrict__ Cp, const float* __restrict__ aux){
    __shared__ __align__(16) ushort As[2][OBM * BK];
    __shared__ __align__(16) ushort Bs[2][BN * BK];
    const int wid9 = (blockIdx.x & 7) * 64 + (blockIdx.x >> 3);  // nwg=512, bijective
    const int col0 = (wid9 & 7) * BN;
    const int row0 = (wid9 >> 3) * OBM;
    const int tid = threadIdx.x;
    const int lane = tid & 63;
    const int wid = tid >> 6;            // 0..7
    const int wm = wid >> 1, wn = wid & 1;   // wave tile 16x64 (4 row-groups x 2 col-groups)
    f32x4 acc[4] = {};
    const int l8 = lane >> 3;
    const int cs = ((lane & 7) ^ (l8 & 7)) * 8;

    const int NK = E_ / BK;   // 32
    {
        const int R0a = wid * 8;                       // A: 8 waves x 8 rows = 64
        gld16(A + (size_t)(row0 + R0a + l8) * E_ + cs, &As[0][R0a * BK]);
        #pragma unroll
        for (int i = 0; i < 2; ++i){
            const int R0 = wid * 16 + i * 8;           // B: 8 waves x 16 rows = 128
            gld16(Bm + (size_t)(col0 + R0 + l8) * E_ + cs, &Bs[0][R0 * BK]);
        }
    }
    __syncthreads();
    int cur = 0;
    for (int ki = 0; ki < NK; ++ki){
        if (ki + 1 < NK){
            const int k0 = (ki + 1) * BK;
            const int R0a = wid * 8;
            gld16(A + (size_t)(row0 + R0a + l8) * E_ + k0 + cs, &As[cur^1][R0a * BK]);
            #pragma unroll
            for (int i = 0; i < 2; ++i){
                const int R0 = wid * 16 + i * 8;
                gld16(Bm + (size_t)(col0 + R0 + l8) * E_ + k0 + cs, &Bs[cur^1][R0 * BK]);
            }
        }
        #pragma unroll
        for (int kk = 0; kk < 2; ++kk){
            bf16x8 af, bfr[4];
            const int krow = lane & 15;
            const int kcol = ((kk * 4 + (lane >> 4)) ^ (krow & 7)) * 8;
            af = *(const bf16x8*)(&As[cur][(wm*16 + krow) * BK + kcol]);
            #pragma unroll
            for (int ni = 0; ni < 4; ++ni)
                bfr[ni] = *(const bf16x8*)(&Bs[cur][(wn*64 + ni*16 + krow) * BK + kcol]);
            #pragma unroll
            for (int ni = 0; ni < 4; ++ni)
                acc[ni] = __builtin_amdgcn_mfma_f32_16x16x32_bf16(af, bfr[ni], acc[ni], 0, 0, 0);
        }
        __syncthreads();
        cur ^= 1;
    }
    #pragma unroll
    for (int ni = 0; ni < 4; ++ni)
        #pragma unroll
        for (int j = 0; j < 4; ++j){
            int r = row0 + wm*16 + (lane >> 4) * 4 + j;
            int c = col0 + wn*64 + ni*16 + (lane & 15);
            size_t idx = (size_t)r * D_ + c;
            Cp[idx] = acc[ni][j] + aux[idx];
        }
}

// ---------------- C96 GEMM, split-K, CBM=64, 512 threads (r23) ----------------
#define CBM 64
__global__ __launch_bounds__(512, 4)
void gemm_c96_sk(const ushort* __restrict__ A, const ushort* __restrict__ Bm,
                 float* __restrict__ part){
    __shared__ __align__(16) ushort As[CBM * BK];
    __shared__ __align__(16) ushort Bs[128 * BK];
    const int ks = blockIdx.x;
    const int row0 = blockIdx.y * CBM;
    const int tid = threadIdx.x;
    const int lane = tid & 63;
    const int wid = tid >> 6;            // 0..7
    const int wm = wid >> 1, wn = wid & 1;   // wave tile 16x64
    f32x4 acc[4] = {};
    const int l8 = lane >> 3;
    const int cs = ((lane & 7) ^ (l8 & 7)) * 8;

    for (int k0 = ks * (E_ / KS_); k0 < (ks + 1) * (E_ / KS_); k0 += BK){
        {
            const int R0a = wid * 8;
            gld16(A + (size_t)(row0 + R0a + l8) * E_ + k0 + cs, As + R0a * BK);
            #pragma unroll
            for (int i = 0; i < 2; ++i){
                const int R0 = wid * 16 + i * 8;
                gld16(Bm + (size_t)(R0 + l8) * E_ + k0 + cs, Bs + R0 * BK);
            }
        }
        __syncthreads();
        #pragma unroll
        for (int kk = 0; kk < 2; ++kk){
            bf16x8 af, bfr[4];
            const int krow = lane & 15;
            const int kcol = ((kk * 4 + (lane >> 4)) ^ (krow & 7)) * 8;
            af = *(const bf16x8*)(As + (wm*16 + krow) * BK + kcol);
            #pragma unroll
            for (int ni = 0; ni < 4; ++ni)
                bfr[ni] = *(const bf16x8*)(Bs + (wn*64 + ni*16 + krow) * BK + kcol);
            #pragma unroll
            for (int ni = 0; ni < 4; ++ni)
                acc[ni] = __builtin_amdgcn_mfma_f32_16x16x32_bf16(af, bfr[ni], acc[ni], 0, 0, 0);
        }
        __syncthreads();
    }
    float* dst = part + (size_t)ks * M_ * 128;
    #pragma unroll
    for (int ni = 0; ni < 4; ++ni)
        #pragma unroll
        for (int j = 0; j < 4; ++j){
            int r = row0 + wm*16 + (lane >> 4) * 4 + j;
            int c = wn*64 + ni*16 + (lane & 15);
            dst[(size_t)r * 128 + c] = acc[ni][j];
        }
}

__global__ __launch_bounds__(256) void c96_reduce_k(const float* __restrict__ part,
                                                    ushort* __restrict__ C96){
    int i4 = blockIdx.x * 256 + threadIdx.x;     // over M_*128/4
    float4 a = *(const float4*)(part + (size_t)i4 * 4);
    #pragma unroll
    for (int k = 1; k < KS_; ++k){
        float4 b = *(const float4*)(part + (size_t)k * M_ * 128 + (size_t)i4 * 4);
        a.x += b.x; a.y += b.y; a.z += b.z; a.w += b.w;
    }
    ushort4 o;
    o.x = f2bf(a.x); o.y = f2bf(a.y); o.z = f2bf(a.z); o.w = f2bf(a.w);
    *(ushort4*)(C96 + (size_t)i4 * 4) = o;
}

// ---------------- causal depthwise conv1d + silu -> bf16 (coalesced taps) ----------------
__global__ __launch_bounds__(256) void conv_silu_k(const ushort* __restrict__ xpre,
                                                   const float* __restrict__ cwT,
                                                   const float* __restrict__ conv_b,
                                                   ushort* __restrict__ xb){
    int i4 = blockIdx.x * 256 + threadIdx.x;
    if (i4 >= M_ * E_ / 4) return;
    int idx = i4 * 4;
    int e = idx & (E_ - 1);
    int bl = idx >> 11;
    int t = bl & (L_ - 1);
    float4 b4 = *(const float4*)(conv_b + e);
    float a0 = b4.x, a1 = b4.y, a2 = b4.z, a3 = b4.w;
    #pragma unroll
    for (int k = 0; k < 4; ++k){
        int dt = 3 - k;
        if (t >= dt){
            ushort4 xv = *(const ushort4*)(xpre + idx - dt * E_);
            float4 wv = *(const float4*)(cwT + (size_t)k * E_ + e);
            a0 += bf2f(xv.x) * wv.x;
            a1 += bf2f(xv.y) * wv.y;
            a2 += bf2f(xv.z) * wv.z;
            a3 += bf2f(xv.w) * wv.w;
        }
    }
    ushort4 sb;
    sb.x = f2bf(fast_silu(a0));
    sb.y = f2bf(fast_silu(a1));
    sb.z = f2bf(fast_silu(a2));
    sb.w = f2bf(fast_silu(a3));
    *(ushort4*)(xb + idx) = sb;
}

// ---------------- chunk-parallel selective scan, delta fused via MFMA ----------------
#define SF2 36   // f32 tile stride (144B, 16B-aligned)
#define SYD 20   // sy stride

__device__ __forceinline__ void seg_swz(int& b, int& s, int& e0){
    int lin = blockIdx.x + 128 * (blockIdx.y + 16 * blockIdx.z);   // nwg = 4096
    int swz = (lin & 7) * 512 + (lin >> 3);                        // bijective
    e0 = (swz & 127) * 16;
    s  = (swz >> 7) & 15;
    b  = swz >> 11;
}

// grid (E_/16, SSEG, B_), block 256 = 16 e x 16 n
__global__ __launch_bounds__(256, 8) void seg1_k(const ushort* __restrict__ xb,
                                              const ushort* __restrict__ C96,
                                              const ushort* __restrict__ wd2b,
                                              const float* __restrict__ wd2_bias,
                                              const float* __restrict__ A_log,
                                              float* __restrict__ F,
                                              float* __restrict__ segdt){
    int b, s, e0; seg_swz(b, s, e0);
    const int tid = threadIdx.x;
    const int lane = tid & 63, wid = tid >> 6;
    const int n = tid & 15, ei = tid >> 4;
    const int e = e0 + ei;
    const float Aen2 = -__expf(A_log[e * N_ + n]) * LOG2E;
    float h = 0.f;
    __shared__ __align__(16) ushort sxr[CH][72];
    __shared__ __align__(16) ushort swd2[16][72];
    __shared__ __align__(16) ushort sxu[16][40];
    __shared__ float sd[16][SF2], sdx[16][SF2], sB[16][SF2];
    __shared__ float ssdt[2][16];
    const int tq = tid >> 3, qc = tid & 7;   // row 0..31, col-group 0..7

    if (tid < 128){
        int r = tid >> 3, cc = (tid & 7) * 8;
        *(uint4*)&swd2[r][cc] = *(const uint4*)(wd2b + (size_t)(e0 + r) * DR_ + cc);
    }
    const float bias = wd2_bias[e0 + (lane & 15)];
    float psdt = 0.f;   // producer-lane partial sum of delta over its t-slice

    for (int c = 0; c < LSEG / CH; ++c){
        int t0 = s * LSEG + c * CH;
        size_t row = (size_t)(b * L_ + t0 + tq);
        *(uint4*)&sxr[tq][qc * 8] = *(const uint4*)(C96 + row * 128 + qc * 8);
        ushort2 rB = *(const ushort2*)(C96 + row * 128 + 64 + qc * 2);
        ushort2 xu = *(const ushort2*)(xb + row * E_ + e0 + qc * 2);
        sB[qc*2+0][tq] = bf2f(rB.x); sB[qc*2+1][tq] = bf2f(rB.y);
        sxu[qc*2+0][tq] = xu.x; sxu[qc*2+1][tq] = xu.y;
        __syncthreads();
        // fused delta: waves 0,1 each compute one 16-t x 16-e tile
        if (wid < 2){
            f32x4 dacc = {};
            #pragma unroll
            for (int kk = 0; kk < 2; ++kk){
                bf16x8 af = *(const bf16x8*)&sxr[wid*16 + (lane & 15)][kk*32 + (lane >> 4)*8];
                bf16x8 bf = *(const bf16x8*)&swd2[lane & 15][kk*32 + (lane >> 4)*8];
                dacc = __builtin_amdgcn_mfma_f32_16x16x32_bf16(af, bf, dacc, 0, 0, 0);
            }
            const int crow = lane & 15;
            const int ttc = wid*16 + (lane >> 4)*4;
            float4 dv;
            dv.x = softplus_f(dacc[0] + bias);
            dv.y = softplus_f(dacc[1] + bias);
            dv.z = softplus_f(dacc[2] + bias);
            dv.w = softplus_f(dacc[3] + bias);
            *(float4*)&sd[crow][ttc] = dv;
            psdt += dv.x + dv.y + dv.z + dv.w;
            ushort4 xu4 = *(const ushort4*)&sxu[crow][ttc];
            float4 dxv;
            dxv.x = dv.x * bf2f(xu4.x); dxv.y = dv.y * bf2f(xu4.y);
            dxv.z = dv.z * bf2f(xu4.z); dxv.w = dv.w * bf2f(xu4.w);
            *(float4*)&sdx[crow][ttc] = dxv;
        }
        __syncthreads();
        #pragma unroll
        for (int t = 0; t < CH; t += 4){
            float4 d4  = *(const float4*)&sd[ei][t];
            float4 dx4 = *(const float4*)&sdx[ei][t];
            float4 b4  = *(const float4*)&sB[n][t];
            h = fexp2(d4.x*Aen2)*h + dx4.x*b4.x;
            h = fexp2(d4.y*Aen2)*h + dx4.y*b4.y;
            h = fexp2(d4.z*Aen2)*h + dx4.z*b4.z;
            h = fexp2(d4.w*Aen2)*h + dx4.w*b4.w;
        }
        __syncthreads();
    }
    // producer-lane sdt reduce
    if (wid < 2){
        psdt += __shfl_xor(psdt, 16);
        psdt += __shfl_xor(psdt, 32);
        if (lane < 16) ssdt[wid][lane] = psdt;
    }
    size_t base = ((size_t)(b * SSEG + s) * E_ + e) * N_ + n;
    F[base] = h;
    __syncthreads();
    if (tid < 16)
        segdt[(size_t)(b * SSEG + s) * E_ + e0 + tid] = ssdt[0][tid] + ssdt[1][tid];
}

// sequential carry over SSEG segments per (b,e,n)
__global__ __launch_bounds__(256) void carry_k(const float* __restrict__ F,
                                               const float* __restrict__ segdt,
                                               const float* __restrict__ A_log,
                                               float* __restrict__ carr){
    int idx = blockIdx.x * 256 + threadIdx.x;
    int n = idx & 15;
    int e = (idx >> 4) & (E_ - 1);
    int b = idx >> 15;
    const float Aen2 = -__expf(A_log[e * N_ + n]) * LOG2E;
    float c = 0.f;
    #pragma unroll
    for (int s = 0; s < SSEG; ++s){
        size_t base = ((size_t)(b * SSEG + s) * E_ + e) * N_ + n;
        carr[base] = c;
        float P = fexp2(Aen2 * segdt[(size_t)(b * SSEG + s) * E_ + e]);
        c = P * c + F[base];
    }
}

// grid (E_/16, SSEG, B_), block 256; gate fused into store
__global__ __launch_bounds__(256, 8) void seg2_k(const ushort* __restrict__ xb,
                                              const ushort* __restrict__ C96,
                                              const ushort* __restrict__ wd2b,
                                              const float* __restrict__ wd2_bias,
                                              const float* __restrict__ A_log,
                                              const float* __restrict__ carr,
                                              const ushort* __restrict__ skipb,
                                              const float* __restrict__ W_D,
                                              ushort* __restrict__ y2){
    int b, s, e0; seg_swz(b, s, e0);
    const int tid = threadIdx.x;
    const int lane = tid & 63, wid = tid >> 6;
    const int n = tid & 15, ei = tid >> 4;
    const int e = e0 + ei;
    const float Aen2 = -__expf(A_log[e * N_ + n]) * LOG2E;
    float h = carr[((size_t)(b * SSEG + s) * E_ + e) * N_ + n];
    __shared__ __align__(16) ushort sxr[CH][72];
    __shared__ __align__(16) ushort swd2[16][72];
    __shared__ __align__(16) ushort sxu[16][40];
    __shared__ float sd[16][SF2], sdx[16][SF2], sB[16][SF2], sC[16][SF2];
    __shared__ float sy[CH][SYD];
    const int tq = tid >> 3, qc = tid & 7;

    if (tid < 128){
        int r = tid >> 3, cc = (tid & 7) * 8;
        *(uint4*)&swd2[r][cc] = *(const uint4*)(wd2b + (size_t)(e0 + r) * DR_ + cc);
    }
    const float bias = wd2_bias[e0 + (lane & 15)];
    const float wv0 = W_D[e0 + qc * 2], wv1 = W_D[e0 + qc * 2 + 1];

    for (int c = 0; c < LSEG / CH; ++c){
        int t0 = s * LSEG + c * CH;
        size_t row = (size_t)(b * L_ + t0 + tq);
        *(uint4*)&sxr[tq][qc * 8] = *(const uint4*)(C96 + row * 128 + qc * 8);
        ushort2 rB = *(const ushort2*)(C96 + row * 128 + 64 + qc * 2);
        ushort2 rC = *(const ushort2*)(C96 + row * 128 + 80 + qc * 2);
        ushort2 xu = *(const ushort2*)(xb + row * E_ + e0 + qc * 2);
        ushort2 sv_pre = *(const ushort2*)(skipb + row * E_ + e0 + qc * 2);  // gate prefetch
        sB[qc*2+0][tq] = bf2f(rB.x); sB[qc*2+1][tq] = bf2f(rB.y);
        sC[qc*2+0][tq] = bf2f(rC.x); sC[qc*2+1][tq] = bf2f(rC.y);
        sxu[qc*2+0][tq] = xu.x; sxu[qc*2+1][tq] = xu.y;
        __syncthreads();
        if (wid < 2){
            f32x4 dacc = {};
            #pragma unroll
            for (int kk = 0; kk < 2; ++kk){
                bf16x8 af = *(const bf16x8*)&sxr[wid*16 + (lane & 15)][kk*32 + (lane >> 4)*8];
                bf16x8 bf = *(const bf16x8*)&swd2[lane & 15][kk*32 + (lane >> 4)*8];
                dacc = __builtin_amdgcn_mfma_f32_16x16x32_bf16(af, bf, dacc, 0, 0, 0);
            }
            const int crow = lane & 15;
            const int ttc = wid*16 + (lane >> 4)*4;
            float4 dv;
            dv.x = softplus_f(dacc[0] + bias);
            dv.y = softplus_f(dacc[1] + bias);
            dv.z = softplus_f(dacc[2] + bias);
            dv.w = softplus_f(dacc[3] + bias);
            *(float4*)&sd[crow][ttc] = dv;
            ushort4 xu4 = *(const ushort4*)&sxu[crow][ttc];
            float4 dxv;
            dxv.x = dv.x * bf2f(xu4.x); dxv.y = dv.y * bf2f(xu4.y);
            dxv.z = dv.z * bf2f(xu4.z); dxv.w = dv.w * bf2f(xu4.w);
            *(float4*)&sdx[crow][ttc] = dxv;
        }
        __syncthreads();
        #pragma unroll
        for (int t = 0; t < CH; t += 4){
            float4 d4  = *(const float4*)&sd[ei][t];
            float4 dx4 = *(const float4*)&sdx[ei][t];
            float4 b4  = *(const float4*)&sB[n][t];
            float4 c4  = *(const float4*)&sC[n][t];
            float y0, y1, y2v, y3;
            h = fexp2(d4.x*Aen2)*h + dx4.x*b4.x;  y0 = h * c4.x;
            h = fexp2(d4.y*Aen2)*h + dx4.y*b4.y;  y1 = h * c4.y;
            h = fexp2(d4.z*Aen2)*h + dx4.z*b4.z;  y2v = h * c4.z;
            h = fexp2(d4.w*Aen2)*h + dx4.w*b4.w;  y3 = h * c4.w;
            // 4-value 16-lane reduce via DPP (zero DS), bit-identical to xor butterfly
            float s01 = (n & 1) ? y0 : y1;
            float r01 = DPP_F(s01, 0xB1);        // quad_perm [1,0,3,2] == xor1
            float s23 = (n & 1) ? y2v : y3;
            float r23 = DPP_F(s23, 0xB1);
            float va, vb;
            if (n & 1){ va = y1 + r01; vb = y3 + r23; }
            else      { va = y0 + r01; vb = y2v + r23; }
            float s2 = (n & 2) ? va : vb;
            float r2 = DPP_F(s2, 0x4E);          // quad_perm [2,3,0,1] == xor2
            float v = ((n & 2) ? vb : va) + r2;
            v += DPP_F(v, 0x124);                // row_ror:4  (xor4-equivalent sum)
            v += DPP_F(v, 0x128);                // row_ror:8  (xor8-equivalent sum)
            if (n < 4) sy[t + n][ei] = v;
        }
        __syncthreads();
        {
            // fused gate: y2 = (y + W_D*x) * silu(skip) -> bf16 (skip prefetched)
            size_t orow = (size_t)(b * L_ + t0 + tq);
            float yv0 = sy[tq][qc*2], yv1 = sy[tq][qc*2+1];
            float xs0 = bf2f(sxu[qc*2+0][tq]), xs1 = bf2f(sxu[qc*2+1][tq]);
            float sk0 = bf2f(sv_pre.x), sk1 = bf2f(sv_pre.y);
            ushort2 o;
            o.x = f2bf((yv0 + wv0 * xs0) * fast_silu(sk0));
            o.y = f2bf((yv1 + wv1 * xs1) * fast_silu(sk1));
            *(ushort2*)(y2 + orow * E_ + e0 + qc * 2) = o;
        }
        __syncthreads();
    }
}

// ---------------- launch ----------------
extern "C" void kernel_launch(void* const* d_in, const int* in_sizes, int n_in,
                              void* d_out, int out_size, void* d_ws, size_t ws_size,
                              hipStream_t stream){
    const float* resid  = (const float*)d_in[0];
    const float* norm_w = (const float*)d_in[1];
    const float* skip_w = (const float*)d_in[2];
    const float* in_w   = (const float*)d_in[3];
    const float* conv_w = (const float*)d_in[4];
    const float* conv_b = (const float*)d_in[5];
    const float* wd1    = (const float*)d_in[6];
    const float* wd2    = (const float*)d_in[7];
    const float* wd2_b  = (const float*)d_in[8];
    const float* wB     = (const float*)d_in[9];
    const float* wC     = (const float*)d_in[10];
    const float* A_log  = (const float*)d_in[11];
    const float* W_D    = (const float*)d_in[12];
    const float* out_w  = (const float*)d_in[13];
    float* out = (float*)d_out;

    char* ws = (char*)d_ws;
    size_t off = 0;
    auto alloc = [&](size_t bytes) -> char* {
        char* p = ws + off;
        off += (bytes + 255) & ~(size_t)255;
        return p;
    };
    char* alias_base = ws;
    ushort* wis_b   = (ushort*)alloc((size_t)2 * E_ * D_ * 2);  // 8MB stacked [in_w; skip_w]
    ushort* xn_b    = (ushort*)alloc((size_t)M_ * D_ * 2);      // 8MB
    ushort* xpre_b  = (ushort*)alloc((size_t)M_ * E_ * 2);      // 16MB
    float*  part_buf= (float*)alias_base;                       // 16MB alias (KS_*M_*128*4)
    ushort* wo_b    = (ushort*)alloc((size_t)D_ * E_ * 2);       // 4MB
    ushort* wd2_bf  = (ushort*)alloc((size_t)E_ * DR_ * 2);      // 256KB
    ushort* W96_b   = (ushort*)alloc((size_t)128 * E_ * 2);      // 512KB
    float*  cwT_b   = (float*)alloc((size_t)4 * E_ * 4);         // 32KB transposed taps
    ushort* skip_b  = (ushort*)alloc((size_t)M_ * E_ * 2);       // 16MB
    ushort* xb_b    = (ushort*)alloc((size_t)M_ * E_ * 2);       // 16MB
    ushort* C96_b   = (ushort*)alloc((size_t)M_ * 128 * 2);      // 1MB
    float*  scr     = (float*)alloc((size_t)9 * 1024 * 1024);    // 9MB scratch
    ushort* y2_b    = (ushort*)alloc((size_t)M_ * E_ * 2);       // 16MB
    float* F_buf    = scr;
    float* carr_buf = scr + (size_t)B_ * SSEG * E_ * N_;
    float* segdt_buf= scr + (size_t)2 * B_ * SSEG * E_ * N_;
    (void)ws_size; (void)in_sizes; (void)n_in; (void)out_size;

    const int thr = 256;

    prep_k<<<(PR8 + 255)/256, thr, 0, stream>>>(in_w, skip_w, out_w, wd2, wd1, wB, wC, conv_w,
                                                wis_b, wo_b, wd2_bf, W96_b, cwT_b);

    rmsnorm_k<<<M_, thr, 0, stream>>>(resid, norm_w, xn_b);

    gemm_dual_k<<<1024, 512, 0, stream>>>(xn_b, wis_b, xpre_b, skip_b);

    conv_silu_k<<<(M_*E_/4 + 255)/256, thr, 0, stream>>>(xpre_b, cwT_b, conv_b, xb_b);

    gemm_c96_sk<<<dim3(KS_, M_/CBM), 512, 0, stream>>>(xb_b, W96_b, part_buf);
    c96_reduce_k<<<(M_*128/4)/256, thr, 0, stream>>>(part_buf, C96_b);

    seg1_k<<<dim3(E_/16, SSEG, B_), thr, 0, stream>>>(xb_b, C96_b, wd2_bf, wd2_b, A_log, F_buf, segdt_buf);
    carry_k<<<(B_*E_*N_)/256, thr, 0, stream>>>(F_buf, segdt_buf, A_log, carr_buf);
    seg2_k<<<dim3(E_/16, SSEG, B_), thr, 0, stream>>>(xb_b, C96_b, wd2_bf, wd2_b, A_log, carr_buf,
                                                      skip_b, W_D, y2_b);

    gemm_out_k<<<512, 512, 0, stream>>>(y2_b, wo_b, out, resid);
}